// Round 12
// baseline (378.725 us; speedup 1.0000x reference)
//
#include <hip/hip_runtime.h>
#include <hip/hip_bf16.h>

typedef unsigned int u32;
typedef unsigned long long u64;
using bf16x8 = __attribute__((ext_vector_type(8))) short;
using f32x4  = __attribute__((ext_vector_type(4))) float;

#define QKV_STRIDE 12582912u   // elements per q/k/v tensor (512*3*256*32)
#define WS_NEED    100663296ull

__device__ __forceinline__ float bl(u32 u) { return __uint_as_float(u << 16); }
__device__ __forceinline__ float bh(u32 u) { return __uint_as_float(u & 0xffff0000u); }
__device__ __forceinline__ unsigned short bfbits(float f) {
    __hip_bfloat16 b = __float2bfloat16(f);
    return *(unsigned short*)&b;
}
__device__ __forceinline__ u32 pack2(float f0, float f1) {
    return ((u32)bfbits(f1) << 16) | (u32)bfbits(f0);
}
__device__ __forceinline__ u64 pack4(float f0, float f1, float f2, float f3) {
    return ((u64)pack2(f2, f3) << 32) | (u64)pack2(f0, f1);
}

#define MFMA(a, b, c) __builtin_amdgcn_mfma_f32_16x16x32_bf16(a, b, c, 0, 0, 0)

// ---------------- guard: ws too small -> sentinel 1000 ----------------
__global__ __launch_bounds__(256) void k_fill(float* __restrict__ out, int n)
{
    int i = blockIdx.x * 256 + threadIdx.x;
    if (i < n) out[i] = 1000.0f;
}

// ---------------- K0a: f32->bf16 qkv/proj weights into d_out tail ----------------
// d_out tail is dead until k_mlp (last dispatch); qkvw_b read@3, projw_b @5.
__global__ __launch_bounds__(256) void k_wcvt_a(const float* __restrict__ qkvw,
                                                const float* __restrict__ pw,
                                                u64* __restrict__ wq,
                                                u64* __restrict__ wp)
{
    int i = blockIdx.x * 256 + threadIdx.x;   // 9216 float4 total
    if (i < 6912) {
        float4 v = ((const float4*)qkvw)[i];
        wq[i] = pack4(v.x, v.y, v.z, v.w);
    } else if (i < 9216) {
        int j = i - 6912;
        float4 v = ((const float4*)pw)[j];
        wp[j] = pack4(v.x, v.y, v.z, v.w);
    }
}

// ---------------- K0b: f32->bf16 fc1/fc2 weights into ws head (after addln2) ----------------
// pbuf region [0,24MB) is dead after k_addln2; k_mlp reads these.
__global__ __launch_bounds__(256) void k_wcvt_b(const float* __restrict__ f1w,
                                                const float* __restrict__ f2w,
                                                u64* __restrict__ wf1,
                                                u64* __restrict__ wf2)
{
    int i = blockIdx.x * 256 + threadIdx.x;   // 18432 float4 total
    if (i < 9216) {
        float4 v = ((const float4*)f1w)[i];
        wf1[i] = pack4(v.x, v.y, v.z, v.w);
    } else if (i < 18432) {
        int j = i - 9216;
        float4 v = ((const float4*)f2w)[j];
        wf2[j] = pack4(v.x, v.y, v.z, v.w);
    }
}

// ---------------- K1: coalesced gather + LayerNorm1 -> h (bf16) [unchanged] ----------------
__global__ __launch_bounds__(256) void k_ln1_c(const float* __restrict__ x,
                                               const float* __restrict__ g1,
                                               const float* __restrict__ b1,
                                               u32* __restrict__ h)
{
    __shared__ float xs[96 * 128];
    __shared__ float ps[256], pss[256], mr[128], rs[128];
    int blk = blockIdx.x;
    int hh = blk & 127, d = (blk >> 7) & 3, bb = blk >> 9;
    long base = (long)bb * 6291456 + (long)d * 16384 + hh * 128;
    for (int i = threadIdx.x; i < 3072; i += 256) {
        int c = i >> 5, w4 = i & 31;
        ((float4*)xs)[i] = *(const float4*)(x + base + (long)c * 65536 + w4 * 4);
    }
    __syncthreads();

    int tid = threadIdx.x, half = tid >> 7, ww = tid & 127;
    int c0 = half * 48;
    float s = 0.f, ssq = 0.f;
    #pragma unroll 8
    for (int c = c0; c < c0 + 48; ++c) {
        float v = xs[c * 128 + ww];
        s += v; ssq += v * v;
    }
    ps[tid] = s; pss[tid] = ssq;
    __syncthreads();
    if (half == 0) {
        float st = ps[ww] + ps[128 + ww], sst = pss[ww] + pss[128 + ww];
        float mean = st * (1.f / 96.f);
        float var  = sst * (1.f / 96.f) - mean * mean;
        mr[ww] = mean; rs[ww] = rsqrtf(var + 1e-5f);
    }
    __syncthreads();
    float mean = mr[ww], rstd = rs[ww];

    int w = (bb << 8) + (hh >> 3) * 16 + (ww >> 3);
    int t = (w << 8) + d * 64 + (hh & 7) * 8 + (ww & 7);
    uint4* hq = (uint4*)(h + (long)t * 48 + half * 24);
    #pragma unroll
    for (int k = 0; k < 6; ++k) {
        int c = c0 + 8 * k;
        u32 q0 = pack2((xs[(c+0)*128+ww]-mean)*rstd*g1[c+0]+b1[c+0],
                       (xs[(c+1)*128+ww]-mean)*rstd*g1[c+1]+b1[c+1]);
        u32 q1 = pack2((xs[(c+2)*128+ww]-mean)*rstd*g1[c+2]+b1[c+2],
                       (xs[(c+3)*128+ww]-mean)*rstd*g1[c+3]+b1[c+3]);
        u32 q2 = pack2((xs[(c+4)*128+ww]-mean)*rstd*g1[c+4]+b1[c+4],
                       (xs[(c+5)*128+ww]-mean)*rstd*g1[c+5]+b1[c+5]);
        u32 q3 = pack2((xs[(c+6)*128+ww]-mean)*rstd*g1[c+6]+b1[c+6],
                       (xs[(c+7)*128+ww]-mean)*rstd*g1[c+7]+b1[c+7]);
        hq[k] = make_uint4(q0, q1, q2, q3);
    }
}

// ---------------- K2: QKV GEMM, LDS-free (bf16 weights from d_out tail) [unchanged] ----------------
__global__ __launch_bounds__(256) void k_qkv_m(const __hip_bfloat16* __restrict__ h,
                                               const __hip_bfloat16* __restrict__ wb,
                                               const float* __restrict__ qkvb,
                                               __hip_bfloat16* __restrict__ qkv)
{
    int tid = threadIdx.x;
    int wave = tid >> 6, lane = tid & 63;
    int quad = lane >> 4, l16 = lane & 15;
    int mbase = blockIdx.x * 64 + wave * 16;

    const __hip_bfloat16* ap = h + (long)(mbase + l16) * 96 + quad * 8;
    bf16x8 A0 = *(const bf16x8*)(ap);
    bf16x8 A1 = *(const bf16x8*)(ap + 32);
    bf16x8 A2 = *(const bf16x8*)(ap + 64);

    int tok0 = mbase + quad * 4;
    int w = tok0 >> 8, nn = tok0 & 255;

    for (int nt = 0; nt < 18; ++nt) {
        int n0 = nt * 16;
        const __hip_bfloat16* bp = wb + (n0 + l16) * 96 + quad * 8;
        bf16x8 B0 = *(const bf16x8*)(bp);
        bf16x8 B1 = *(const bf16x8*)(bp + 32);
        bf16x8 B2 = *(const bf16x8*)(bp + 64);
        int r    = n0 + l16;
        int type = n0 / 96;
        int head = (n0 % 96) / 32;
        int dd   = r & 31;
        float bias = qkvb[r];
        float scl  = (type == 0) ? 0.17677669529663687f : 1.0f;
        long tbase = (long)type * QKV_STRIDE;
        f32x4 acc = {0.f, 0.f, 0.f, 0.f};
        acc = MFMA(A0, B0, acc);
        acc = MFMA(A1, B1, acc);
        acc = MFMA(A2, B2, acc);
        long dst0 = tbase + (long)(w * 3 + head) * 8192 + nn * 32 + dd;
        #pragma unroll
        for (int rg = 0; rg < 4; ++rg)
            qkv[dst0 + (long)rg * 32] = __float2bfloat16((acc[rg] + bias) * scl);
    }
}

// ---------------- K3: window attention via MFMA [unchanged] ----------------
__global__ __launch_bounds__(256, 6) void k_attn_m(const __hip_bfloat16* __restrict__ qkv,
                                                   const float* __restrict__ btab,
                                                   __hip_bfloat16* __restrict__ o)
{
    __shared__ short vt[32 * 264];        // V^T [d][key], pitch 264 (16B-aligned)
    __shared__ float bsT[31 * 33];        // bias transposed: bsT[dx][dy], odd pitch
    int wh = blockIdx.x, head = wh % 3, w = wh / 3;
    int tid = threadIdx.x;

    const u32* vg = (const u32*)(qkv + 2u * QKV_STRIDE + (long)wh * 8192);
    for (int idx = tid; idx < 4096; idx += 256) {
        u32 pv = vg[idx];
        int kr = idx >> 4, d0 = (idx & 15) * 2;
        vt[d0 * 264 + kr]       = (short)(pv & 0xffffu);
        vt[(d0 + 1) * 264 + kr] = (short)(pv >> 16);
    }
    for (int idx = tid; idx < 961; idx += 256) {
        int c2 = idx / 31, r2 = idx - c2 * 31;
        bsT[c2 * 33 + r2] = btab[(r2 * 31 + c2) * 3 + head];
    }
    __syncthreads();

    int wave = tid >> 6, lane = tid & 63, quad = lane >> 4, l16 = lane & 15;
    const __hip_bfloat16* qb = qkv + (long)wh * 8192;
    const __hip_bfloat16* kb = qkv + QKV_STRIDE + (long)wh * 8192;

    int addrA = ((((lane >> 4) & 1) << 5) + l16) << 2;   // src lane (quad&1)*32 + l16
    int addrB = addrA + 64;                              // +16 lanes
    int addrI = (quad * 20) << 2;                        // lane 20*quad (+4*rg): inv for query quad*4+rg
    bool hiq  = (quad >= 2);

    #pragma unroll 1
    for (int g = 0; g < 4; ++g) {
        int qg = wave * 4 + g;
        bf16x8 qf = *(const bf16x8*)(qb + (qg * 16 + l16) * 32 + quad * 8);
        f32x4 a0 = {0.f, 0.f, 0.f, 0.f}, a1 = {0.f, 0.f, 0.f, 0.f};
        float lsum = 0.f;

        #pragma unroll 1
        for (int qt = 0; qt < 4; ++qt) {       // quarters of 64 keys, SEQUENTIAL
            f32x4 s[4];
            #pragma unroll
            for (int k4 = 0; k4 < 4; ++k4) {
                int kt = qt * 4 + k4;
                bf16x8 kkv = *(const bf16x8*)(kb + (kt * 16 + l16) * 32 + quad * 8);
                f32x4 z = {0.f, 0.f, 0.f, 0.f};
                s[k4] = MFMA(kkv, qf, z);
            }
            #pragma unroll
            for (int rg = 0; rg < 4; ++rg) {
                const float* bb = &bsT[(l16 - quad * 4 + 15 - rg) * 33 + qg];
                #pragma unroll
                for (int k4 = 0; k4 < 4; ++k4)
                    s[k4][rg] += bb[15 - qt * 4 - k4];
            }
            f32x4 vs = {0.f, 0.f, 0.f, 0.f};
            #pragma unroll
            for (int k4 = 0; k4 < 4; ++k4) {
                f32x4 e;
                #pragma unroll
                for (int rg = 0; rg < 4; ++rg) e[rg] = __expf(s[k4][rg]);
                s[k4] = e;
                vs += e;
            }
            lsum += vs[0] + vs[1] + vs[2] + vs[3];

            #pragma unroll
            for (int k2l = 0; k2l < 2; ++k2l) {
                int k2 = qt * 2 + k2l;
                u32 pe0 = pack2(s[2 * k2l][0],     s[2 * k2l][1]);
                u32 pe1 = pack2(s[2 * k2l][2],     s[2 * k2l][3]);
                u32 po0 = pack2(s[2 * k2l + 1][0], s[2 * k2l + 1][1]);
                u32 po1 = pack2(s[2 * k2l + 1][2], s[2 * k2l + 1][3]);
                u32 e0 = (u32)__builtin_amdgcn_ds_bpermute(addrA, (int)pe0);
                u32 o0 = (u32)__builtin_amdgcn_ds_bpermute(addrA, (int)po0);
                u32 e1 = (u32)__builtin_amdgcn_ds_bpermute(addrA, (int)pe1);
                u32 o1 = (u32)__builtin_amdgcn_ds_bpermute(addrA, (int)po1);
                u32 e2 = (u32)__builtin_amdgcn_ds_bpermute(addrB, (int)pe0);
                u32 o2 = (u32)__builtin_amdgcn_ds_bpermute(addrB, (int)po0);
                u32 e3 = (u32)__builtin_amdgcn_ds_bpermute(addrB, (int)pe1);
                u32 o3 = (u32)__builtin_amdgcn_ds_bpermute(addrB, (int)po1);
                union { u32 u[4]; bf16x8 v; } pu;
                pu.u[0] = hiq ? o0 : e0;
                pu.u[1] = hiq ? o1 : e1;
                pu.u[2] = hiq ? o2 : e2;
                pu.u[3] = hiq ? o3 : e3;
                bf16x8 v0 = *(const bf16x8*)&vt[l16 * 264 + k2 * 32 + quad * 8];
                bf16x8 v1 = *(const bf16x8*)&vt[(16 + l16) * 264 + k2 * 32 + quad * 8];
                a0 = MFMA(pu.v, v0, a0);
                a1 = MFMA(pu.v, v1, a1);
            }
        }

        lsum += __shfl_xor(lsum, 16);
        lsum += __shfl_xor(lsum, 32);
        float inv = 1.f / lsum;          // valid for query qg*16 + l16

        #pragma unroll
        for (int rg = 0; rg < 4; ++rg) {
            float irg = __uint_as_float(
                (u32)__builtin_amdgcn_ds_bpermute(addrI + (rg << 2), (int)__float_as_uint(inv)));
            int qrow = qg * 16 + quad * 4 + rg;
            __hip_bfloat16* op = o + (long)(w * 256 + qrow) * 96 + head * 32;
            op[l16]      = __float2bfloat16(a0[rg] * irg);
            op[16 + l16] = __float2bfloat16(a1[rg] * irg);
        }
    }
}

// ---------------- K4a: proj, LDS-free (bf16 weights from d_out tail) [unchanged] ----------------
__global__ __launch_bounds__(256) void k_proj_nr(const __hip_bfloat16* __restrict__ o,
                                                 const __hip_bfloat16* __restrict__ wb,
                                                 const float* __restrict__ pb,
                                                 __hip_bfloat16* __restrict__ pbuf)
{
    int tid = threadIdx.x;
    int wave = tid >> 6, lane = tid & 63;
    int quad = lane >> 4, l16 = lane & 15;
    int mbase = blockIdx.x * 64 + wave * 16;

    const __hip_bfloat16* ap = o + (long)(mbase + l16) * 96 + quad * 8;
    bf16x8 A0 = *(const bf16x8*)(ap);
    bf16x8 A1 = *(const bf16x8*)(ap + 32);
    bf16x8 A2 = *(const bf16x8*)(ap + 64);

    int tok0 = mbase + quad * 4;

    for (int nt = 0; nt < 6; ++nt) {
        int n0 = nt * 16;
        const __hip_bfloat16* bp = wb + (n0 + l16) * 96 + quad * 8;
        bf16x8 B0 = *(const bf16x8*)(bp);
        bf16x8 B1 = *(const bf16x8*)(bp + 32);
        bf16x8 B2 = *(const bf16x8*)(bp + 64);
        int c = n0 + l16;
        float bias = pb[c];
        f32x4 acc = {0.f, 0.f, 0.f, 0.f};
        acc = MFMA(A0, B0, acc);
        acc = MFMA(A1, B1, acc);
        acc = MFMA(A2, B2, acc);
        #pragma unroll
        for (int rg = 0; rg < 4; ++rg)
            pbuf[(long)(tok0 + rg) * 96 + c] = __float2bfloat16(acc[rg] + bias);
    }
}

// ---------------- K4b: residual + LN2 -> t2 (bf16), h2 (bf16) [unchanged] ----------------
__global__ __launch_bounds__(256) void k_addln2(const float* __restrict__ x,
                                                const __hip_bfloat16* __restrict__ pbuf,
                                                const float* __restrict__ g2,
                                                const float* __restrict__ b2,
                                                u32* __restrict__ t2,
                                                u32* __restrict__ h2)
{
    __shared__ float xs[96 * 128];
    __shared__ float ps[256], pss[256], mr[128], rs[128];
    int blk = blockIdx.x;
    int hh = blk & 127, d = (blk >> 7) & 3, bb = blk >> 9;
    long base = (long)bb * 6291456 + (long)d * 16384 + hh * 128;
    for (int i = threadIdx.x; i < 3072; i += 256) {
        int c = i >> 5, w4 = i & 31;
        ((float4*)xs)[i] = *(const float4*)(x + base + (long)c * 65536 + w4 * 4);
    }
    __syncthreads();

    int tid = threadIdx.x, half = tid >> 7, ww = tid & 127;
    int c0 = half * 48;
    int w = (bb << 8) + (hh >> 3) * 16 + (ww >> 3);
    int t = (w << 8) + d * 64 + (hh & 7) * 8 + (ww & 7);

    const uint4* pr4 = (const uint4*)((const u32*)pbuf + (long)t * 48 + half * 24);
    float pv[48];
    float s = 0.f, ssq = 0.f;
    #pragma unroll
    for (int k6 = 0; k6 < 6; ++k6) {
        uint4 q = pr4[k6];
        u32 uu[4] = {q.x, q.y, q.z, q.w};
        #pragma unroll
        for (int j = 0; j < 4; ++j) {
            int c = c0 + 8 * k6 + 2 * j;
            float v0 = bl(uu[j]) + xs[c * 128 + ww];
            float v1 = bh(uu[j]) + xs[(c + 1) * 128 + ww];
            pv[8 * k6 + 2 * j]     = v0;
            pv[8 * k6 + 2 * j + 1] = v1;
            s += v0 + v1; ssq += v0 * v0 + v1 * v1;
        }
    }
    ps[tid] = s; pss[tid] = ssq;
    __syncthreads();
    if (half == 0) {
        float st = ps[ww] + ps[128 + ww], sst = pss[ww] + pss[128 + ww];
        float mean = st * (1.f / 96.f);
        float var  = sst * (1.f / 96.f) - mean * mean;
        mr[ww] = mean; rs[ww] = rsqrtf(var + 1e-5f);
    }
    __syncthreads();
    float mean = mr[ww], rstd = rs[ww];

    uint4* t2q = (uint4*)(t2 + (long)t * 48 + half * 24);
    uint4* hq  = (uint4*)(h2 + (long)t * 48 + half * 24);
    #pragma unroll
    for (int k = 0; k < 6; ++k) {
        int c = c0 + 8 * k;
        u32 t0v = pack2(pv[8*k+0], pv[8*k+1]);
        u32 t1v = pack2(pv[8*k+2], pv[8*k+3]);
        u32 t2v = pack2(pv[8*k+4], pv[8*k+5]);
        u32 t3v = pack2(pv[8*k+6], pv[8*k+7]);
        t2q[k] = make_uint4(t0v, t1v, t2v, t3v);
        u32 q0 = pack2((pv[8*k+0]-mean)*rstd*g2[c+0]+b2[c+0],
                       (pv[8*k+1]-mean)*rstd*g2[c+1]+b2[c+1]);
        u32 q1 = pack2((pv[8*k+2]-mean)*rstd*g2[c+2]+b2[c+2],
                       (pv[8*k+3]-mean)*rstd*g2[c+3]+b2[c+3]);
        u32 q2 = pack2((pv[8*k+4]-mean)*rstd*g2[c+4]+b2[c+4],
                       (pv[8*k+5]-mean)*rstd*g2[c+5]+b2[c+5]);
        u32 q3 = pack2((pv[8*k+6]-mean)*rstd*g2[c+6]+b2[c+6],
                       (pv[8*k+7]-mean)*rstd*g2[c+7]+b2[c+7]);
        hq[k] = make_uint4(q0, q1, q2, q3);
    }
}

// ---------------- K5: FUSED MLP: fc1 + GELU + fc2 + residual -> out ----------------
// v12: m1 (100MB) never touches HBM. fc1 uses SWAPPED operands MFMA(w1,h2)
// (attn-verified mapping: lane(quad,l16) -> m1[token=l16][col=nt*16+quad*4+rg]),
// so each lane packs 4 consecutive cols of ONE token -> 1 u64 LDS write/nt into
// a per-wave [16 tokens][392] tile. fc2 reads standard A-fragments from the same
// rows (no cross-wave sharing). Saves 201MB HBM + 3 dispatches vs fc1/fc2 x2.
__global__ __launch_bounds__(256) void k_mlp(const __hip_bfloat16* __restrict__ h2,
                                             const __hip_bfloat16* __restrict__ w1b,
                                             const float* __restrict__ f1b,
                                             const __hip_bfloat16* __restrict__ w2b,
                                             const float* __restrict__ f2b,
                                             const __hip_bfloat16* __restrict__ t2,
                                             float* __restrict__ out)
{
    __shared__ short m1t[64 * 392];       // [token-in-block][col], pitch 392
    int tid = threadIdx.x;
    int wave = tid >> 6, lane = tid & 63;
    int quad = lane >> 4, l16 = lane & 15;
    int mbase = blockIdx.x * 64 + wave * 16;   // wave's 16 tokens

    const __hip_bfloat16* ap = h2 + (long)(mbase + l16) * 96 + quad * 8;
    bf16x8 Y0 = *(const bf16x8*)(ap);
    bf16x8 Y1 = *(const bf16x8*)(ap + 32);
    bf16x8 Y2 = *(const bf16x8*)(ap + 64);

    const float is2 = 0.70710678118654752440f;
    short* mrow = &m1t[(wave * 16 + l16) * 392];

    for (int nt = 0; nt < 24; ++nt) {
        const __hip_bfloat16* xp = w1b + (long)(nt * 16 + l16) * 96 + quad * 8;
        bf16x8 X0 = *(const bf16x8*)(xp);
        bf16x8 X1 = *(const bf16x8*)(xp + 32);
        bf16x8 X2 = *(const bf16x8*)(xp + 64);
        f32x4 acc = {0.f, 0.f, 0.f, 0.f};
        acc = MFMA(X0, Y0, acc);
        acc = MFMA(X1, Y1, acc);
        acc = MFMA(X2, Y2, acc);
        // lane holds m1[token=l16][nt*16 + quad*4 + rg]
        float4 bb4 = *(const float4*)(f1b + nt * 16 + quad * 4);
        float v0 = acc[0] + bb4.x, v1 = acc[1] + bb4.y;
        float v2 = acc[2] + bb4.z, v3 = acc[3] + bb4.w;
        v0 = 0.5f * v0 * (1.f + erff(v0 * is2));
        v1 = 0.5f * v1 * (1.f + erff(v1 * is2));
        v2 = 0.5f * v2 * (1.f + erff(v2 * is2));
        v3 = 0.5f * v3 * (1.f + erff(v3 * is2));
        *(u64*)&mrow[nt * 16 + quad * 4] = pack4(v0, v1, v2, v3);
    }
    __syncthreads();

    int tok0 = mbase + quad * 4;
    for (int ct = 0; ct < 6; ++ct) {
        int c = ct * 16 + l16;
        const __hip_bfloat16* bp = w2b + (long)c * 384 + quad * 8;
        float bias = f2b[c];
        f32x4 acc = {0.f, 0.f, 0.f, 0.f};
        #pragma unroll
        for (int kc = 0; kc < 12; ++kc) {
            bf16x8 Af = *(const bf16x8*)&mrow[kc * 32 + quad * 8];
            bf16x8 Bf = *(const bf16x8*)(bp + kc * 32);
            acc = MFMA(Af, Bf, acc);
        }
        #pragma unroll
        for (int rg = 0; rg < 4; ++rg) {
            long g = (long)(tok0 + rg) * 96 + c;
            out[g] = __bfloat162float(t2[g]) + acc[rg] + bias;
        }
    }
}

extern "C" void kernel_launch(void* const* d_in, const int* in_sizes, int n_in,
                              void* d_out, int out_size, void* d_ws, size_t ws_size,
                              hipStream_t stream)
{
    const float* x     = (const float*)d_in[0];
    const float* qkvw  = (const float*)d_in[1];
    const float* qkvb  = (const float*)d_in[2];
    const float* projw = (const float*)d_in[3];
    const float* projb = (const float*)d_in[4];
    const float* btab  = (const float*)d_in[5];
    const float* ln1g  = (const float*)d_in[6];
    const float* ln1b  = (const float*)d_in[7];
    const float* ln2g  = (const float*)d_in[8];
    const float* ln2b  = (const float*)d_in[9];
    const float* fc1w  = (const float*)d_in[10];
    const float* fc1b  = (const float*)d_in[11];
    const float* fc2w  = (const float*)d_in[12];
    const float* fc2b  = (const float*)d_in[13];
    float* out = (float*)d_out;

    if (ws_size < WS_NEED) {
        k_fill<<<49152, 256, 0, stream>>>(out, out_size);
        return;
    }

    // ws lifetimes (96 MiB):
    //  [0,72)  : qkv(bf16) -> { pbuf bf16 [0,24) -> {wf1b,wf2b 147KB} ; t2 bf16 [48,72) }
    //  [72,96) : h(bf16) -> o(bf16) -> h2(bf16)
    // d_out tail (last 73728B): qkvw_b+projw_b until k_mlp overwrites out (last dispatch).
    char* ws = (char*)d_ws;
    __hip_bfloat16* qkvB  = (__hip_bfloat16*)(ws);
    __hip_bfloat16* pbuf  = (__hip_bfloat16*)(ws);
    __hip_bfloat16* wf1b  = (__hip_bfloat16*)(ws);             // 73728 B
    __hip_bfloat16* wf2b  = (__hip_bfloat16*)(ws + 73728);     // 73728 B
    __hip_bfloat16* t2buf = (__hip_bfloat16*)(ws + 50331648);
    __hip_bfloat16* hbuf  = (__hip_bfloat16*)(ws + 75497472);
    __hip_bfloat16* obuf  = hbuf;
    __hip_bfloat16* h2buf = hbuf;

    char* ob = (char*)d_out;
    __hip_bfloat16* wqb = (__hip_bfloat16*)(ob + 50257920);    // 55296 B
    __hip_bfloat16* wpb = (__hip_bfloat16*)(ob + 50313216);    // 18432 B (ends 50331648)

    k_wcvt_a<<<36,   256, 0, stream>>>(qkvw, projw, (u64*)wqb, (u64*)wpb);
    k_ln1_c <<<1024, 256, 0, stream>>>(x, ln1g, ln1b, (u32*)hbuf);
    k_qkv_m <<<2048, 256, 0, stream>>>(hbuf, wqb, qkvb, qkvB);
    k_attn_m<<<1536, 256, 0, stream>>>(qkvB, btab, obuf);
    k_proj_nr<<<2048, 256, 0, stream>>>(obuf, wpb, projb, pbuf);
    k_addln2<<<1024, 256, 0, stream>>>(x, pbuf, ln2g, ln2b, (u32*)t2buf, (u32*)h2buf);
    k_wcvt_b<<<72,   256, 0, stream>>>(fc1w, fc2w, (u64*)wf1b, (u64*)wf2b);
    k_mlp   <<<2048, 256, 0, stream>>>(h2buf, wf1b, fc1b, wf2b, fc2b, t2buf, out);
}

// Round 13
// 375.523 us; speedup vs baseline: 1.0085x; 1.0085x over previous
//
#include <hip/hip_runtime.h>
#include <hip/hip_bf16.h>

typedef unsigned int u32;
typedef unsigned long long u64;
using bf16x8 = __attribute__((ext_vector_type(8))) short;
using f32x4  = __attribute__((ext_vector_type(4))) float;

#define QKV_STRIDE 12582912u   // elements per q/k/v tensor (512*3*256*32)
#define WS_NEED    100663296ull

__device__ __forceinline__ float bl(u32 u) { return __uint_as_float(u << 16); }
__device__ __forceinline__ float bh(u32 u) { return __uint_as_float(u & 0xffff0000u); }
__device__ __forceinline__ unsigned short bfbits(float f) {
    __hip_bfloat16 b = __float2bfloat16(f);
    return *(unsigned short*)&b;
}
__device__ __forceinline__ u32 pack2(float f0, float f1) {
    return ((u32)bfbits(f1) << 16) | (u32)bfbits(f0);
}
__device__ __forceinline__ u64 pack4(float f0, float f1, float f2, float f3) {
    return ((u64)pack2(f2, f3) << 32) | (u64)pack2(f0, f1);
}

#define MFMA(a, b, c) __builtin_amdgcn_mfma_f32_16x16x32_bf16(a, b, c, 0, 0, 0)

// ---------------- guard: ws too small -> sentinel 1000 ----------------
__global__ __launch_bounds__(256) void k_fill(float* __restrict__ out, int n)
{
    int i = blockIdx.x * 256 + threadIdx.x;
    if (i < n) out[i] = 1000.0f;
}

// ---------------- K0a: f32->bf16 qkv/proj weights into d_out tail ----------------
__global__ __launch_bounds__(256) void k_wcvt_a(const float* __restrict__ qkvw,
                                                const float* __restrict__ pw,
                                                u64* __restrict__ wq,
                                                u64* __restrict__ wp)
{
    int i = blockIdx.x * 256 + threadIdx.x;   // 9216 float4 total
    if (i < 6912) {
        float4 v = ((const float4*)qkvw)[i];
        wq[i] = pack4(v.x, v.y, v.z, v.w);
    } else if (i < 9216) {
        int j = i - 6912;
        float4 v = ((const float4*)pw)[j];
        wp[j] = pack4(v.x, v.y, v.z, v.w);
    }
}

// ---------------- K0b: f32->bf16 fc1/fc2 weights into ws head (after addln2) ----------------
__global__ __launch_bounds__(256) void k_wcvt_b(const float* __restrict__ f1w,
                                                const float* __restrict__ f2w,
                                                u64* __restrict__ wf1,
                                                u64* __restrict__ wf2)
{
    int i = blockIdx.x * 256 + threadIdx.x;   // 18432 float4 total
    if (i < 9216) {
        float4 v = ((const float4*)f1w)[i];
        wf1[i] = pack4(v.x, v.y, v.z, v.w);
    } else if (i < 18432) {
        int j = i - 9216;
        float4 v = ((const float4*)f2w)[j];
        wf2[j] = pack4(v.x, v.y, v.z, v.w);
    }
}

// ---------------- K1: coalesced gather + LayerNorm1 -> h (bf16) [unchanged] ----------------
__global__ __launch_bounds__(256) void k_ln1_c(const float* __restrict__ x,
                                               const float* __restrict__ g1,
                                               const float* __restrict__ b1,
                                               u32* __restrict__ h)
{
    __shared__ float xs[96 * 128];
    __shared__ float ps[256], pss[256], mr[128], rs[128];
    int blk = blockIdx.x;
    int hh = blk & 127, d = (blk >> 7) & 3, bb = blk >> 9;
    long base = (long)bb * 6291456 + (long)d * 16384 + hh * 128;
    for (int i = threadIdx.x; i < 3072; i += 256) {
        int c = i >> 5, w4 = i & 31;
        ((float4*)xs)[i] = *(const float4*)(x + base + (long)c * 65536 + w4 * 4);
    }
    __syncthreads();

    int tid = threadIdx.x, half = tid >> 7, ww = tid & 127;
    int c0 = half * 48;
    float s = 0.f, ssq = 0.f;
    #pragma unroll 8
    for (int c = c0; c < c0 + 48; ++c) {
        float v = xs[c * 128 + ww];
        s += v; ssq += v * v;
    }
    ps[tid] = s; pss[tid] = ssq;
    __syncthreads();
    if (half == 0) {
        float st = ps[ww] + ps[128 + ww], sst = pss[ww] + pss[128 + ww];
        float mean = st * (1.f / 96.f);
        float var  = sst * (1.f / 96.f) - mean * mean;
        mr[ww] = mean; rs[ww] = rsqrtf(var + 1e-5f);
    }
    __syncthreads();
    float mean = mr[ww], rstd = rs[ww];

    int w = (bb << 8) + (hh >> 3) * 16 + (ww >> 3);
    int t = (w << 8) + d * 64 + (hh & 7) * 8 + (ww & 7);
    uint4* hq = (uint4*)(h + (long)t * 48 + half * 24);
    #pragma unroll
    for (int k = 0; k < 6; ++k) {
        int c = c0 + 8 * k;
        u32 q0 = pack2((xs[(c+0)*128+ww]-mean)*rstd*g1[c+0]+b1[c+0],
                       (xs[(c+1)*128+ww]-mean)*rstd*g1[c+1]+b1[c+1]);
        u32 q1 = pack2((xs[(c+2)*128+ww]-mean)*rstd*g1[c+2]+b1[c+2],
                       (xs[(c+3)*128+ww]-mean)*rstd*g1[c+3]+b1[c+3]);
        u32 q2 = pack2((xs[(c+4)*128+ww]-mean)*rstd*g1[c+4]+b1[c+4],
                       (xs[(c+5)*128+ww]-mean)*rstd*g1[c+5]+b1[c+5]);
        u32 q3 = pack2((xs[(c+6)*128+ww]-mean)*rstd*g1[c+6]+b1[c+6],
                       (xs[(c+7)*128+ww]-mean)*rstd*g1[c+7]+b1[c+7]);
        hq[k] = make_uint4(q0, q1, q2, q3);
    }
}

// ---------------- K2: QKV GEMM, LDS-free (bf16 weights from d_out tail) [unchanged] ----------------
__global__ __launch_bounds__(256) void k_qkv_m(const __hip_bfloat16* __restrict__ h,
                                               const __hip_bfloat16* __restrict__ wb,
                                               const float* __restrict__ qkvb,
                                               __hip_bfloat16* __restrict__ qkv)
{
    int tid = threadIdx.x;
    int wave = tid >> 6, lane = tid & 63;
    int quad = lane >> 4, l16 = lane & 15;
    int mbase = blockIdx.x * 64 + wave * 16;

    const __hip_bfloat16* ap = h + (long)(mbase + l16) * 96 + quad * 8;
    bf16x8 A0 = *(const bf16x8*)(ap);
    bf16x8 A1 = *(const bf16x8*)(ap + 32);
    bf16x8 A2 = *(const bf16x8*)(ap + 64);

    int tok0 = mbase + quad * 4;
    int w = tok0 >> 8, nn = tok0 & 255;

    for (int nt = 0; nt < 18; ++nt) {
        int n0 = nt * 16;
        const __hip_bfloat16* bp = wb + (n0 + l16) * 96 + quad * 8;
        bf16x8 B0 = *(const bf16x8*)(bp);
        bf16x8 B1 = *(const bf16x8*)(bp + 32);
        bf16x8 B2 = *(const bf16x8*)(bp + 64);
        int r    = n0 + l16;
        int type = n0 / 96;
        int head = (n0 % 96) / 32;
        int dd   = r & 31;
        float bias = qkvb[r];
        float scl  = (type == 0) ? 0.17677669529663687f : 1.0f;
        long tbase = (long)type * QKV_STRIDE;
        f32x4 acc = {0.f, 0.f, 0.f, 0.f};
        acc = MFMA(A0, B0, acc);
        acc = MFMA(A1, B1, acc);
        acc = MFMA(A2, B2, acc);
        long dst0 = tbase + (long)(w * 3 + head) * 8192 + nn * 32 + dd;
        #pragma unroll
        for (int rg = 0; rg < 4; ++rg)
            qkv[dst0 + (long)rg * 32] = __float2bfloat16((acc[rg] + bias) * scl);
    }
}

// ---------------- K3: window attention via MFMA [unchanged] ----------------
__global__ __launch_bounds__(256, 6) void k_attn_m(const __hip_bfloat16* __restrict__ qkv,
                                                   const float* __restrict__ btab,
                                                   __hip_bfloat16* __restrict__ o)
{
    __shared__ short vt[32 * 264];        // V^T [d][key], pitch 264 (16B-aligned)
    __shared__ float bsT[31 * 33];        // bias transposed: bsT[dx][dy], odd pitch
    int wh = blockIdx.x, head = wh % 3, w = wh / 3;
    int tid = threadIdx.x;

    const u32* vg = (const u32*)(qkv + 2u * QKV_STRIDE + (long)wh * 8192);
    for (int idx = tid; idx < 4096; idx += 256) {
        u32 pv = vg[idx];
        int kr = idx >> 4, d0 = (idx & 15) * 2;
        vt[d0 * 264 + kr]       = (short)(pv & 0xffffu);
        vt[(d0 + 1) * 264 + kr] = (short)(pv >> 16);
    }
    for (int idx = tid; idx < 961; idx += 256) {
        int c2 = idx / 31, r2 = idx - c2 * 31;
        bsT[c2 * 33 + r2] = btab[(r2 * 31 + c2) * 3 + head];
    }
    __syncthreads();

    int wave = tid >> 6, lane = tid & 63, quad = lane >> 4, l16 = lane & 15;
    const __hip_bfloat16* qb = qkv + (long)wh * 8192;
    const __hip_bfloat16* kb = qkv + QKV_STRIDE + (long)wh * 8192;

    int addrA = ((((lane >> 4) & 1) << 5) + l16) << 2;   // src lane (quad&1)*32 + l16
    int addrB = addrA + 64;                              // +16 lanes
    int addrI = (quad * 20) << 2;                        // lane 20*quad (+4*rg): inv for query quad*4+rg
    bool hiq  = (quad >= 2);

    #pragma unroll 1
    for (int g = 0; g < 4; ++g) {
        int qg = wave * 4 + g;
        bf16x8 qf = *(const bf16x8*)(qb + (qg * 16 + l16) * 32 + quad * 8);
        f32x4 a0 = {0.f, 0.f, 0.f, 0.f}, a1 = {0.f, 0.f, 0.f, 0.f};
        float lsum = 0.f;

        #pragma unroll 1
        for (int qt = 0; qt < 4; ++qt) {       // quarters of 64 keys, SEQUENTIAL
            f32x4 s[4];
            #pragma unroll
            for (int k4 = 0; k4 < 4; ++k4) {
                int kt = qt * 4 + k4;
                bf16x8 kkv = *(const bf16x8*)(kb + (kt * 16 + l16) * 32 + quad * 8);
                f32x4 z = {0.f, 0.f, 0.f, 0.f};
                s[k4] = MFMA(kkv, qf, z);
            }
            #pragma unroll
            for (int rg = 0; rg < 4; ++rg) {
                const float* bb = &bsT[(l16 - quad * 4 + 15 - rg) * 33 + qg];
                #pragma unroll
                for (int k4 = 0; k4 < 4; ++k4)
                    s[k4][rg] += bb[15 - qt * 4 - k4];
            }
            f32x4 vs = {0.f, 0.f, 0.f, 0.f};
            #pragma unroll
            for (int k4 = 0; k4 < 4; ++k4) {
                f32x4 e;
                #pragma unroll
                for (int rg = 0; rg < 4; ++rg) e[rg] = __expf(s[k4][rg]);
                s[k4] = e;
                vs += e;
            }
            lsum += vs[0] + vs[1] + vs[2] + vs[3];

            #pragma unroll
            for (int k2l = 0; k2l < 2; ++k2l) {
                int k2 = qt * 2 + k2l;
                u32 pe0 = pack2(s[2 * k2l][0],     s[2 * k2l][1]);
                u32 pe1 = pack2(s[2 * k2l][2],     s[2 * k2l][3]);
                u32 po0 = pack2(s[2 * k2l + 1][0], s[2 * k2l + 1][1]);
                u32 po1 = pack2(s[2 * k2l + 1][2], s[2 * k2l + 1][3]);
                u32 e0 = (u32)__builtin_amdgcn_ds_bpermute(addrA, (int)pe0);
                u32 o0 = (u32)__builtin_amdgcn_ds_bpermute(addrA, (int)po0);
                u32 e1 = (u32)__builtin_amdgcn_ds_bpermute(addrA, (int)pe1);
                u32 o1 = (u32)__builtin_amdgcn_ds_bpermute(addrA, (int)po1);
                u32 e2 = (u32)__builtin_amdgcn_ds_bpermute(addrB, (int)pe0);
                u32 o2 = (u32)__builtin_amdgcn_ds_bpermute(addrB, (int)po0);
                u32 e3 = (u32)__builtin_amdgcn_ds_bpermute(addrB, (int)pe1);
                u32 o3 = (u32)__builtin_amdgcn_ds_bpermute(addrB, (int)po1);
                union { u32 u[4]; bf16x8 v; } pu;
                pu.u[0] = hiq ? o0 : e0;
                pu.u[1] = hiq ? o1 : e1;
                pu.u[2] = hiq ? o2 : e2;
                pu.u[3] = hiq ? o3 : e3;
                bf16x8 v0 = *(const bf16x8*)&vt[l16 * 264 + k2 * 32 + quad * 8];
                bf16x8 v1 = *(const bf16x8*)&vt[(16 + l16) * 264 + k2 * 32 + quad * 8];
                a0 = MFMA(pu.v, v0, a0);
                a1 = MFMA(pu.v, v1, a1);
            }
        }

        lsum += __shfl_xor(lsum, 16);
        lsum += __shfl_xor(lsum, 32);
        float inv = 1.f / lsum;          // valid for query qg*16 + l16

        #pragma unroll
        for (int rg = 0; rg < 4; ++rg) {
            float irg = __uint_as_float(
                (u32)__builtin_amdgcn_ds_bpermute(addrI + (rg << 2), (int)__float_as_uint(inv)));
            int qrow = qg * 16 + quad * 4 + rg;
            __hip_bfloat16* op = o + (long)(w * 256 + qrow) * 96 + head * 32;
            op[l16]      = __float2bfloat16(a0[rg] * irg);
            op[16 + l16] = __float2bfloat16(a1[rg] * irg);
        }
    }
}

// ---------------- K4a: proj, LDS-free (bf16 weights from d_out tail) [unchanged] ----------------
__global__ __launch_bounds__(256) void k_proj_nr(const __hip_bfloat16* __restrict__ o,
                                                 const __hip_bfloat16* __restrict__ wb,
                                                 const float* __restrict__ pb,
                                                 __hip_bfloat16* __restrict__ pbuf)
{
    int tid = threadIdx.x;
    int wave = tid >> 6, lane = tid & 63;
    int quad = lane >> 4, l16 = lane & 15;
    int mbase = blockIdx.x * 64 + wave * 16;

    const __hip_bfloat16* ap = o + (long)(mbase + l16) * 96 + quad * 8;
    bf16x8 A0 = *(const bf16x8*)(ap);
    bf16x8 A1 = *(const bf16x8*)(ap + 32);
    bf16x8 A2 = *(const bf16x8*)(ap + 64);

    int tok0 = mbase + quad * 4;

    for (int nt = 0; nt < 6; ++nt) {
        int n0 = nt * 16;
        const __hip_bfloat16* bp = wb + (n0 + l16) * 96 + quad * 8;
        bf16x8 B0 = *(const bf16x8*)(bp);
        bf16x8 B1 = *(const bf16x8*)(bp + 32);
        bf16x8 B2 = *(const bf16x8*)(bp + 64);
        int c = n0 + l16;
        float bias = pb[c];
        f32x4 acc = {0.f, 0.f, 0.f, 0.f};
        acc = MFMA(A0, B0, acc);
        acc = MFMA(A1, B1, acc);
        acc = MFMA(A2, B2, acc);
        #pragma unroll
        for (int rg = 0; rg < 4; ++rg)
            pbuf[(long)(tok0 + rg) * 96 + c] = __float2bfloat16(acc[rg] + bias);
    }
}

// ---------------- K4b: residual + LN2 -> t2 (bf16), h2 (bf16) [unchanged] ----------------
__global__ __launch_bounds__(256) void k_addln2(const float* __restrict__ x,
                                                const __hip_bfloat16* __restrict__ pbuf,
                                                const float* __restrict__ g2,
                                                const float* __restrict__ b2,
                                                u32* __restrict__ t2,
                                                u32* __restrict__ h2)
{
    __shared__ float xs[96 * 128];
    __shared__ float ps[256], pss[256], mr[128], rs[128];
    int blk = blockIdx.x;
    int hh = blk & 127, d = (blk >> 7) & 3, bb = blk >> 9;
    long base = (long)bb * 6291456 + (long)d * 16384 + hh * 128;
    for (int i = threadIdx.x; i < 3072; i += 256) {
        int c = i >> 5, w4 = i & 31;
        ((float4*)xs)[i] = *(const float4*)(x + base + (long)c * 65536 + w4 * 4);
    }
    __syncthreads();

    int tid = threadIdx.x, half = tid >> 7, ww = tid & 127;
    int c0 = half * 48;
    int w = (bb << 8) + (hh >> 3) * 16 + (ww >> 3);
    int t = (w << 8) + d * 64 + (hh & 7) * 8 + (ww & 7);

    const uint4* pr4 = (const uint4*)((const u32*)pbuf + (long)t * 48 + half * 24);
    float pv[48];
    float s = 0.f, ssq = 0.f;
    #pragma unroll
    for (int k6 = 0; k6 < 6; ++k6) {
        uint4 q = pr4[k6];
        u32 uu[4] = {q.x, q.y, q.z, q.w};
        #pragma unroll
        for (int j = 0; j < 4; ++j) {
            int c = c0 + 8 * k6 + 2 * j;
            float v0 = bl(uu[j]) + xs[c * 128 + ww];
            float v1 = bh(uu[j]) + xs[(c + 1) * 128 + ww];
            pv[8 * k6 + 2 * j]     = v0;
            pv[8 * k6 + 2 * j + 1] = v1;
            s += v0 + v1; ssq += v0 * v0 + v1 * v1;
        }
    }
    ps[tid] = s; pss[tid] = ssq;
    __syncthreads();
    if (half == 0) {
        float st = ps[ww] + ps[128 + ww], sst = pss[ww] + pss[128 + ww];
        float mean = st * (1.f / 96.f);
        float var  = sst * (1.f / 96.f) - mean * mean;
        mr[ww] = mean; rs[ww] = rsqrtf(var + 1e-5f);
    }
    __syncthreads();
    float mean = mr[ww], rstd = rs[ww];

    uint4* t2q = (uint4*)(t2 + (long)t * 48 + half * 24);
    uint4* hq  = (uint4*)(h2 + (long)t * 48 + half * 24);
    #pragma unroll
    for (int k = 0; k < 6; ++k) {
        int c = c0 + 8 * k;
        u32 t0v = pack2(pv[8*k+0], pv[8*k+1]);
        u32 t1v = pack2(pv[8*k+2], pv[8*k+3]);
        u32 t2v = pack2(pv[8*k+4], pv[8*k+5]);
        u32 t3v = pack2(pv[8*k+6], pv[8*k+7]);
        t2q[k] = make_uint4(t0v, t1v, t2v, t3v);
        u32 q0 = pack2((pv[8*k+0]-mean)*rstd*g2[c+0]+b2[c+0],
                       (pv[8*k+1]-mean)*rstd*g2[c+1]+b2[c+1]);
        u32 q1 = pack2((pv[8*k+2]-mean)*rstd*g2[c+2]+b2[c+2],
                       (pv[8*k+3]-mean)*rstd*g2[c+3]+b2[c+3]);
        u32 q2 = pack2((pv[8*k+4]-mean)*rstd*g2[c+4]+b2[c+4],
                       (pv[8*k+5]-mean)*rstd*g2[c+5]+b2[c+5]);
        u32 q3 = pack2((pv[8*k+6]-mean)*rstd*g2[c+6]+b2[c+6],
                       (pv[8*k+7]-mean)*rstd*g2[c+7]+b2[c+7]);
        hq[k] = make_uint4(q0, q1, q2, q3);
    }
}

// ---------------- K5: FUSED MLP v2: thirds-split K (LDS 17.4KB, acc2 in regs) ----------------
// v12 post-mortem: 64x392 tile (50KB) -> 3 blocks/CU; latency-bound at 600GB/s.
// v13: hidden dim split into 3 thirds of 128. Per third: fc1 -> 64x136-pitch LDS
// tile (17408B) -> fc2 partial-accumulates into persistent acc2[6] (exact: fc2 is
// linear in k). LDS no longer the limiter (~5 blocks/CU, reg-bound); phases 3x
// shorter. h-loop pinned unroll 1 (round-7 lesson: scheduling window = live set).
__global__ __launch_bounds__(256) void k_mlp(const __hip_bfloat16* __restrict__ h2,
                                             const __hip_bfloat16* __restrict__ w1b,
                                             const float* __restrict__ f1b,
                                             const __hip_bfloat16* __restrict__ w2b,
                                             const float* __restrict__ f2b,
                                             const __hip_bfloat16* __restrict__ t2,
                                             float* __restrict__ out)
{
    __shared__ short m1t[64 * 136];       // [token-in-block][col-in-third], pitch 136
    int tid = threadIdx.x;
    int wave = tid >> 6, lane = tid & 63;
    int quad = lane >> 4, l16 = lane & 15;
    int mbase = blockIdx.x * 64 + wave * 16;   // wave's 16 tokens

    const __hip_bfloat16* ap = h2 + (long)(mbase + l16) * 96 + quad * 8;
    bf16x8 Y0 = *(const bf16x8*)(ap);
    bf16x8 Y1 = *(const bf16x8*)(ap + 32);
    bf16x8 Y2 = *(const bf16x8*)(ap + 64);

    const float is2 = 0.70710678118654752440f;
    short* mrow = &m1t[(wave * 16 + l16) * 136];

    f32x4 acc2[6];
    #pragma unroll
    for (int ct = 0; ct < 6; ++ct) acc2[ct] = (f32x4){0.f, 0.f, 0.f, 0.f};

    #pragma unroll 1
    for (int h = 0; h < 3; ++h) {
        if (h) __syncthreads();           // protect tile from previous third's readers
        // fc1 for cols [h*128, h*128+128): 8 nt steps
        for (int ntl = 0; ntl < 8; ++ntl) {
            int col0 = h * 128 + ntl * 16;
            const __hip_bfloat16* xp = w1b + (long)(col0 + l16) * 96 + quad * 8;
            bf16x8 X0 = *(const bf16x8*)(xp);
            bf16x8 X1 = *(const bf16x8*)(xp + 32);
            bf16x8 X2 = *(const bf16x8*)(xp + 64);
            f32x4 acc = {0.f, 0.f, 0.f, 0.f};
            acc = MFMA(X0, Y0, acc);
            acc = MFMA(X1, Y1, acc);
            acc = MFMA(X2, Y2, acc);
            // lane holds m1[token=l16][col0 + quad*4 + rg]
            float4 bb4 = *(const float4*)(f1b + col0 + quad * 4);
            float v0 = acc[0] + bb4.x, v1 = acc[1] + bb4.y;
            float v2 = acc[2] + bb4.z, v3 = acc[3] + bb4.w;
            v0 = 0.5f * v0 * (1.f + erff(v0 * is2));
            v1 = 0.5f * v1 * (1.f + erff(v1 * is2));
            v2 = 0.5f * v2 * (1.f + erff(v2 * is2));
            v3 = 0.5f * v3 * (1.f + erff(v3 * is2));
            *(u64*)&mrow[ntl * 16 + quad * 4] = pack4(v0, v1, v2, v3);
        }
        __syncthreads();
        // fc2 partial: k-range [h*128, h*128+128) = 4 kc chunks of 32
        #pragma unroll
        for (int ct = 0; ct < 6; ++ct) {
            int c = ct * 16 + l16;
            const __hip_bfloat16* bp = w2b + (long)c * 384 + h * 128 + quad * 8;
            #pragma unroll
            for (int kc = 0; kc < 4; ++kc) {
                bf16x8 Af = *(const bf16x8*)&mrow[kc * 32 + quad * 8];
                bf16x8 Bf = *(const bf16x8*)(bp + kc * 32);
                acc2[ct] = MFMA(Af, Bf, acc2[ct]);
            }
        }
    }

    int tok0 = mbase + quad * 4;
    #pragma unroll
    for (int ct = 0; ct < 6; ++ct) {
        int c = ct * 16 + l16;
        float bias = f2b[c];
        #pragma unroll
        for (int rg = 0; rg < 4; ++rg) {
            long g = (long)(tok0 + rg) * 96 + c;
            out[g] = __bfloat162float(t2[g]) + acc2[ct][rg] + bias;
        }
    }
}

extern "C" void kernel_launch(void* const* d_in, const int* in_sizes, int n_in,
                              void* d_out, int out_size, void* d_ws, size_t ws_size,
                              hipStream_t stream)
{
    const float* x     = (const float*)d_in[0];
    const float* qkvw  = (const float*)d_in[1];
    const float* qkvb  = (const float*)d_in[2];
    const float* projw = (const float*)d_in[3];
    const float* projb = (const float*)d_in[4];
    const float* btab  = (const float*)d_in[5];
    const float* ln1g  = (const float*)d_in[6];
    const float* ln1b  = (const float*)d_in[7];
    const float* ln2g  = (const float*)d_in[8];
    const float* ln2b  = (const float*)d_in[9];
    const float* fc1w  = (const float*)d_in[10];
    const float* fc1b  = (const float*)d_in[11];
    const float* fc2w  = (const float*)d_in[12];
    const float* fc2b  = (const float*)d_in[13];
    float* out = (float*)d_out;

    if (ws_size < WS_NEED) {
        k_fill<<<49152, 256, 0, stream>>>(out, out_size);
        return;
    }

    // ws lifetimes (96 MiB):
    //  [0,72)  : qkv(bf16) -> { pbuf bf16 [0,24) -> {wf1b,wf2b 147KB} ; t2 bf16 [48,72) }
    //  [72,96) : h(bf16) -> o(bf16) -> h2(bf16)
    // d_out tail (last 73728B): qkvw_b+projw_b until k_mlp overwrites out (last dispatch).
    char* ws = (char*)d_ws;
    __hip_bfloat16* qkvB  = (__hip_bfloat16*)(ws);
    __hip_bfloat16* pbuf  = (__hip_bfloat16*)(ws);
    __hip_bfloat16* wf1b  = (__hip_bfloat16*)(ws);             // 73728 B
    __hip_bfloat16* wf2b  = (__hip_bfloat16*)(ws + 73728);     // 73728 B
    __hip_bfloat16* t2buf = (__hip_bfloat16*)(ws + 50331648);
    __hip_bfloat16* hbuf  = (__hip_bfloat16*)(ws + 75497472);
    __hip_bfloat16* obuf  = hbuf;
    __hip_bfloat16* h2buf = hbuf;

    char* ob = (char*)d_out;
    __hip_bfloat16* wqb = (__hip_bfloat16*)(ob + 50257920);    // 55296 B
    __hip_bfloat16* wpb = (__hip_bfloat16*)(ob + 50313216);    // 18432 B (ends 50331648)

    k_wcvt_a<<<36,   256, 0, stream>>>(qkvw, projw, (u64*)wqb, (u64*)wpb);
    k_ln1_c <<<1024, 256, 0, stream>>>(x, ln1g, ln1b, (u32*)hbuf);
    k_qkv_m <<<2048, 256, 0, stream>>>(hbuf, wqb, qkvb, qkvB);
    k_attn_m<<<1536, 256, 0, stream>>>(qkvB, btab, obuf);
    k_proj_nr<<<2048, 256, 0, stream>>>(obuf, wpb, projb, pbuf);
    k_addln2<<<1024, 256, 0, stream>>>(x, pbuf, ln2g, ln2b, (u32*)t2buf, (u32*)h2buf);
    k_wcvt_b<<<72,   256, 0, stream>>>(fc1w, fc2w, (u64*)wf1b, (u64*)wf2b);
    k_mlp   <<<2048, 256, 0, stream>>>(h2buf, wf1b, fc1b, wf2b, fc2b, t2buf, out);
}

// Round 15
// 374.489 us; speedup vs baseline: 1.0113x; 1.0028x over previous
//
#include <hip/hip_runtime.h>
#include <hip/hip_bf16.h>

typedef unsigned int u32;
typedef unsigned long long u64;
using bf16x8 = __attribute__((ext_vector_type(8))) short;
using f32x4  = __attribute__((ext_vector_type(4))) float;

#define QKV_STRIDE 12582912u   // elements per q/k/v tensor (512*3*256*32)
#define WS_NEED    100663296ull

__device__ __forceinline__ float bl(u32 u) { return __uint_as_float(u << 16); }
__device__ __forceinline__ float bh(u32 u) { return __uint_as_float(u & 0xffff0000u); }
__device__ __forceinline__ unsigned short bfbits(float f) {
    __hip_bfloat16 b = __float2bfloat16(f);
    return *(unsigned short*)&b;
}
__device__ __forceinline__ u32 pack2(float f0, float f1) {
    return ((u32)bfbits(f1) << 16) | (u32)bfbits(f0);
}
__device__ __forceinline__ u64 pack4(float f0, float f1, float f2, float f3) {
    return ((u64)pack2(f2, f3) << 32) | (u64)pack2(f0, f1);
}

#define MFMA(a, b, c) __builtin_amdgcn_mfma_f32_16x16x32_bf16(a, b, c, 0, 0, 0)

// ---------------- guard: ws too small -> sentinel 1000 ----------------
__global__ __launch_bounds__(256) void k_fill(float* __restrict__ out, int n)
{
    int i = blockIdx.x * 256 + threadIdx.x;
    if (i < n) out[i] = 1000.0f;
}

// ---------------- K0: f32->bf16 qkv/proj/fc1 weights into d_out tail (v11) ----------------
__global__ __launch_bounds__(256) void k_wcvt(const float* __restrict__ qkvw,
                                              const float* __restrict__ pw,
                                              const float* __restrict__ f1w,
                                              u64* __restrict__ wq,
                                              u64* __restrict__ wp,
                                              u64* __restrict__ wf1)
{
    int i = blockIdx.x * 256 + threadIdx.x;   // 18432 float4 total
    if (i < 6912) {
        float4 v = ((const float4*)qkvw)[i];
        wq[i] = pack4(v.x, v.y, v.z, v.w);
    } else if (i < 9216) {
        int j = i - 6912;
        float4 v = ((const float4*)pw)[j];
        wp[j] = pack4(v.x, v.y, v.z, v.w);
    } else if (i < 18432) {
        int j = i - 9216;
        float4 v = ((const float4*)f1w)[j];
        wf1[j] = pack4(v.x, v.y, v.z, v.w);
    }
}

// ---------------- K1: gather + LayerNorm1 -> h (bf16); 96x64 tile ----------------
// v14 post-mortem: absmax 5.47 from mis-shifted block decomposition
// (blk = wh2 + 2*hh + 256*d + 1024*bb -> d at bits 8..9, bb at bit 10;
// I wrote >>9/>>11). v15 fixes the two shifts; tile logic unchanged.
__global__ __launch_bounds__(256) void k_ln1_c(const float* __restrict__ x,
                                               const float* __restrict__ g1,
                                               const float* __restrict__ b1,
                                               u32* __restrict__ h)
{
    __shared__ float xs[96 * 64];
    __shared__ float ps[256], pss[256], mr[64], rs[64];
    int blk = blockIdx.x;
    int wh2 = blk & 1, hh = (blk >> 1) & 127, d = (blk >> 8) & 3, bb = blk >> 10;
    long base = (long)bb * 6291456 + (long)d * 16384 + hh * 128 + wh2 * 64;
    for (int i = threadIdx.x; i < 1536; i += 256) {
        int c = i >> 4, w4 = i & 15;
        ((float4*)xs)[i] = *(const float4*)(x + base + (long)c * 65536 + w4 * 4);
    }
    __syncthreads();

    int tid = threadIdx.x, q4 = tid >> 6, wwl = tid & 63;
    int c0 = q4 * 24;
    float s = 0.f, ssq = 0.f;
    #pragma unroll 8
    for (int c = c0; c < c0 + 24; ++c) {
        float v = xs[c * 64 + wwl];
        s += v; ssq += v * v;
    }
    ps[tid] = s; pss[tid] = ssq;
    __syncthreads();
    if (q4 == 0) {
        float st  = ps[wwl]  + ps[64 + wwl]  + ps[128 + wwl]  + ps[192 + wwl];
        float sst = pss[wwl] + pss[64 + wwl] + pss[128 + wwl] + pss[192 + wwl];
        float mean = st * (1.f / 96.f);
        float var  = sst * (1.f / 96.f) - mean * mean;
        mr[wwl] = mean; rs[wwl] = rsqrtf(var + 1e-5f);
    }
    __syncthreads();
    float mean = mr[wwl], rstd = rs[wwl];

    int ww = wh2 * 64 + wwl;
    int w = (bb << 8) + (hh >> 3) * 16 + (ww >> 3);
    int t = (w << 8) + d * 64 + (hh & 7) * 8 + (ww & 7);
    uint4* hq = (uint4*)(h + (long)t * 48 + q4 * 12);
    #pragma unroll
    for (int k = 0; k < 3; ++k) {
        int c = c0 + 8 * k;
        u32 q0 = pack2((xs[(c+0)*64+wwl]-mean)*rstd*g1[c+0]+b1[c+0],
                       (xs[(c+1)*64+wwl]-mean)*rstd*g1[c+1]+b1[c+1]);
        u32 q1 = pack2((xs[(c+2)*64+wwl]-mean)*rstd*g1[c+2]+b1[c+2],
                       (xs[(c+3)*64+wwl]-mean)*rstd*g1[c+3]+b1[c+3]);
        u32 q2 = pack2((xs[(c+4)*64+wwl]-mean)*rstd*g1[c+4]+b1[c+4],
                       (xs[(c+5)*64+wwl]-mean)*rstd*g1[c+5]+b1[c+5]);
        u32 q3 = pack2((xs[(c+6)*64+wwl]-mean)*rstd*g1[c+6]+b1[c+6],
                       (xs[(c+7)*64+wwl]-mean)*rstd*g1[c+7]+b1[c+7]);
        hq[k] = make_uint4(q0, q1, q2, q3);
    }
}

// ---------------- K2: QKV GEMM, LDS-free (bf16 weights from d_out tail) [v11] ----------------
__global__ __launch_bounds__(256) void k_qkv_m(const __hip_bfloat16* __restrict__ h,
                                               const __hip_bfloat16* __restrict__ wb,
                                               const float* __restrict__ qkvb,
                                               __hip_bfloat16* __restrict__ qkv)
{
    int tid = threadIdx.x;
    int wave = tid >> 6, lane = tid & 63;
    int quad = lane >> 4, l16 = lane & 15;
    int mbase = blockIdx.x * 64 + wave * 16;

    const __hip_bfloat16* ap = h + (long)(mbase + l16) * 96 + quad * 8;
    bf16x8 A0 = *(const bf16x8*)(ap);
    bf16x8 A1 = *(const bf16x8*)(ap + 32);
    bf16x8 A2 = *(const bf16x8*)(ap + 64);

    int tok0 = mbase + quad * 4;
    int w = tok0 >> 8, nn = tok0 & 255;

    for (int nt = 0; nt < 18; ++nt) {
        int n0 = nt * 16;
        const __hip_bfloat16* bp = wb + (n0 + l16) * 96 + quad * 8;
        bf16x8 B0 = *(const bf16x8*)(bp);
        bf16x8 B1 = *(const bf16x8*)(bp + 32);
        bf16x8 B2 = *(const bf16x8*)(bp + 64);
        int r    = n0 + l16;
        int type = n0 / 96;
        int head = (n0 % 96) / 32;
        int dd   = r & 31;
        float bias = qkvb[r];
        float scl  = (type == 0) ? 0.17677669529663687f : 1.0f;
        long tbase = (long)type * QKV_STRIDE;
        f32x4 acc = {0.f, 0.f, 0.f, 0.f};
        acc = MFMA(A0, B0, acc);
        acc = MFMA(A1, B1, acc);
        acc = MFMA(A2, B2, acc);
        long dst0 = tbase + (long)(w * 3 + head) * 8192 + nn * 32 + dd;
        #pragma unroll
        for (int rg = 0; rg < 4; ++rg)
            qkv[dst0 + (long)rg * 32] = __float2bfloat16((acc[rg] + bias) * scl);
    }
}

// ---------------- K3: window attention via MFMA [unchanged] ----------------
__global__ __launch_bounds__(256, 6) void k_attn_m(const __hip_bfloat16* __restrict__ qkv,
                                                   const float* __restrict__ btab,
                                                   __hip_bfloat16* __restrict__ o)
{
    __shared__ short vt[32 * 264];        // V^T [d][key], pitch 264 (16B-aligned)
    __shared__ float bsT[31 * 33];        // bias transposed: bsT[dx][dy], odd pitch
    int wh = blockIdx.x, head = wh % 3, w = wh / 3;
    int tid = threadIdx.x;

    const u32* vg = (const u32*)(qkv + 2u * QKV_STRIDE + (long)wh * 8192);
    for (int idx = tid; idx < 4096; idx += 256) {
        u32 pv = vg[idx];
        int kr = idx >> 4, d0 = (idx & 15) * 2;
        vt[d0 * 264 + kr]       = (short)(pv & 0xffffu);
        vt[(d0 + 1) * 264 + kr] = (short)(pv >> 16);
    }
    for (int idx = tid; idx < 961; idx += 256) {
        int c2 = idx / 31, r2 = idx - c2 * 31;
        bsT[c2 * 33 + r2] = btab[(r2 * 31 + c2) * 3 + head];
    }
    __syncthreads();

    int wave = tid >> 6, lane = tid & 63, quad = lane >> 4, l16 = lane & 15;
    const __hip_bfloat16* qb = qkv + (long)wh * 8192;
    const __hip_bfloat16* kb = qkv + QKV_STRIDE + (long)wh * 8192;

    int addrA = ((((lane >> 4) & 1) << 5) + l16) << 2;   // src lane (quad&1)*32 + l16
    int addrB = addrA + 64;                              // +16 lanes
    int addrI = (quad * 20) << 2;                        // lane 20*quad (+4*rg): inv for query quad*4+rg
    bool hiq  = (quad >= 2);

    #pragma unroll 1
    for (int g = 0; g < 4; ++g) {
        int qg = wave * 4 + g;
        bf16x8 qf = *(const bf16x8*)(qb + (qg * 16 + l16) * 32 + quad * 8);
        f32x4 a0 = {0.f, 0.f, 0.f, 0.f}, a1 = {0.f, 0.f, 0.f, 0.f};
        float lsum = 0.f;

        #pragma unroll 1
        for (int qt = 0; qt < 4; ++qt) {       // quarters of 64 keys, SEQUENTIAL
            f32x4 s[4];
            #pragma unroll
            for (int k4 = 0; k4 < 4; ++k4) {
                int kt = qt * 4 + k4;
                bf16x8 kkv = *(const bf16x8*)(kb + (kt * 16 + l16) * 32 + quad * 8);
                f32x4 z = {0.f, 0.f, 0.f, 0.f};
                s[k4] = MFMA(kkv, qf, z);
            }
            #pragma unroll
            for (int rg = 0; rg < 4; ++rg) {
                const float* bb = &bsT[(l16 - quad * 4 + 15 - rg) * 33 + qg];
                #pragma unroll
                for (int k4 = 0; k4 < 4; ++k4)
                    s[k4][rg] += bb[15 - qt * 4 - k4];
            }
            f32x4 vs = {0.f, 0.f, 0.f, 0.f};
            #pragma unroll
            for (int k4 = 0; k4 < 4; ++k4) {
                f32x4 e;
                #pragma unroll
                for (int rg = 0; rg < 4; ++rg) e[rg] = __expf(s[k4][rg]);
                s[k4] = e;
                vs += e;
            }
            lsum += vs[0] + vs[1] + vs[2] + vs[3];

            #pragma unroll
            for (int k2l = 0; k2l < 2; ++k2l) {
                int k2 = qt * 2 + k2l;
                u32 pe0 = pack2(s[2 * k2l][0],     s[2 * k2l][1]);
                u32 pe1 = pack2(s[2 * k2l][2],     s[2 * k2l][3]);
                u32 po0 = pack2(s[2 * k2l + 1][0], s[2 * k2l + 1][1]);
                u32 po1 = pack2(s[2 * k2l + 1][2], s[2 * k2l + 1][3]);
                u32 e0 = (u32)__builtin_amdgcn_ds_bpermute(addrA, (int)pe0);
                u32 o0 = (u32)__builtin_amdgcn_ds_bpermute(addrA, (int)po0);
                u32 e1 = (u32)__builtin_amdgcn_ds_bpermute(addrA, (int)pe1);
                u32 o1 = (u32)__builtin_amdgcn_ds_bpermute(addrA, (int)po1);
                u32 e2 = (u32)__builtin_amdgcn_ds_bpermute(addrB, (int)pe0);
                u32 o2 = (u32)__builtin_amdgcn_ds_bpermute(addrB, (int)po0);
                u32 e3 = (u32)__builtin_amdgcn_ds_bpermute(addrB, (int)pe1);
                u32 o3 = (u32)__builtin_amdgcn_ds_bpermute(addrB, (int)po1);
                union { u32 u[4]; bf16x8 v; } pu;
                pu.u[0] = hiq ? o0 : e0;
                pu.u[1] = hiq ? o1 : e1;
                pu.u[2] = hiq ? o2 : e2;
                pu.u[3] = hiq ? o3 : e3;
                bf16x8 v0 = *(const bf16x8*)&vt[l16 * 264 + k2 * 32 + quad * 8];
                bf16x8 v1 = *(const bf16x8*)&vt[(16 + l16) * 264 + k2 * 32 + quad * 8];
                a0 = MFMA(pu.v, v0, a0);
                a1 = MFMA(pu.v, v1, a1);
            }
        }

        lsum += __shfl_xor(lsum, 16);
        lsum += __shfl_xor(lsum, 32);
        float inv = 1.f / lsum;          // valid for query qg*16 + l16

        #pragma unroll
        for (int rg = 0; rg < 4; ++rg) {
            float irg = __uint_as_float(
                (u32)__builtin_amdgcn_ds_bpermute(addrI + (rg << 2), (int)__float_as_uint(inv)));
            int qrow = qg * 16 + quad * 4 + rg;
            __hip_bfloat16* op = o + (long)(w * 256 + qrow) * 96 + head * 32;
            op[l16]      = __float2bfloat16(a0[rg] * irg);
            op[16 + l16] = __float2bfloat16(a1[rg] * irg);
        }
    }
}

// ---------------- K4a: proj, LDS-free (bf16 weights from d_out tail) [v11] ----------------
__global__ __launch_bounds__(256) void k_proj_nr(const __hip_bfloat16* __restrict__ o,
                                                 const __hip_bfloat16* __restrict__ wb,
                                                 const float* __restrict__ pb,
                                                 __hip_bfloat16* __restrict__ pbuf)
{
    int tid = threadIdx.x;
    int wave = tid >> 6, lane = tid & 63;
    int quad = lane >> 4, l16 = lane & 15;
    int mbase = blockIdx.x * 64 + wave * 16;

    const __hip_bfloat16* ap = o + (long)(mbase + l16) * 96 + quad * 8;
    bf16x8 A0 = *(const bf16x8*)(ap);
    bf16x8 A1 = *(const bf16x8*)(ap + 32);
    bf16x8 A2 = *(const bf16x8*)(ap + 64);

    int tok0 = mbase + quad * 4;

    for (int nt = 0; nt < 6; ++nt) {
        int n0 = nt * 16;
        const __hip_bfloat16* bp = wb + (n0 + l16) * 96 + quad * 8;
        bf16x8 B0 = *(const bf16x8*)(bp);
        bf16x8 B1 = *(const bf16x8*)(bp + 32);
        bf16x8 B2 = *(const bf16x8*)(bp + 64);
        int c = n0 + l16;
        float bias = pb[c];
        f32x4 acc = {0.f, 0.f, 0.f, 0.f};
        acc = MFMA(A0, B0, acc);
        acc = MFMA(A1, B1, acc);
        acc = MFMA(A2, B2, acc);
        #pragma unroll
        for (int rg = 0; rg < 4; ++rg)
            pbuf[(long)(tok0 + rg) * 96 + c] = __float2bfloat16(acc[rg] + bias);
    }
}

// ---------------- K4b: residual + LN2 -> t2, h2; 96x64 tile (shifts fixed) ----------------
__global__ __launch_bounds__(256) void k_addln2(const float* __restrict__ x,
                                                const __hip_bfloat16* __restrict__ pbuf,
                                                const float* __restrict__ g2,
                                                const float* __restrict__ b2,
                                                u32* __restrict__ t2,
                                                u32* __restrict__ h2)
{
    __shared__ float xs[96 * 64];
    __shared__ float ps[256], pss[256], mr[64], rs[64];
    int blk = blockIdx.x;
    int wh2 = blk & 1, hh = (blk >> 1) & 127, d = (blk >> 8) & 3, bb = blk >> 10;
    long base = (long)bb * 6291456 + (long)d * 16384 + hh * 128 + wh2 * 64;
    for (int i = threadIdx.x; i < 1536; i += 256) {
        int c = i >> 4, w4 = i & 15;
        ((float4*)xs)[i] = *(const float4*)(x + base + (long)c * 65536 + w4 * 4);
    }
    __syncthreads();

    int tid = threadIdx.x, q4 = tid >> 6, wwl = tid & 63;
    int c0 = q4 * 24;
    int ww = wh2 * 64 + wwl;
    int w = (bb << 8) + (hh >> 3) * 16 + (ww >> 3);
    int t = (w << 8) + d * 64 + (hh & 7) * 8 + (ww & 7);

    const uint4* pr4 = (const uint4*)((const u32*)pbuf + (long)t * 48 + q4 * 12);
    float pv[24];
    float s = 0.f, ssq = 0.f;
    #pragma unroll
    for (int k6 = 0; k6 < 3; ++k6) {
        uint4 q = pr4[k6];
        u32 uu[4] = {q.x, q.y, q.z, q.w};
        #pragma unroll
        for (int j = 0; j < 4; ++j) {
            int c = c0 + 8 * k6 + 2 * j;
            float v0 = bl(uu[j]) + xs[c * 64 + wwl];
            float v1 = bh(uu[j]) + xs[(c + 1) * 64 + wwl];
            pv[8 * k6 + 2 * j]     = v0;
            pv[8 * k6 + 2 * j + 1] = v1;
            s += v0 + v1; ssq += v0 * v0 + v1 * v1;
        }
    }
    ps[tid] = s; pss[tid] = ssq;
    __syncthreads();
    if (q4 == 0) {
        float st  = ps[wwl]  + ps[64 + wwl]  + ps[128 + wwl]  + ps[192 + wwl];
        float sst = pss[wwl] + pss[64 + wwl] + pss[128 + wwl] + pss[192 + wwl];
        float mean = st * (1.f / 96.f);
        float var  = sst * (1.f / 96.f) - mean * mean;
        mr[wwl] = mean; rs[wwl] = rsqrtf(var + 1e-5f);
    }
    __syncthreads();
    float mean = mr[wwl], rstd = rs[wwl];

    uint4* t2q = (uint4*)(t2 + (long)t * 48 + q4 * 12);
    uint4* hq  = (uint4*)(h2 + (long)t * 48 + q4 * 12);
    #pragma unroll
    for (int k = 0; k < 3; ++k) {
        int c = c0 + 8 * k;
        u32 t0v = pack2(pv[8*k+0], pv[8*k+1]);
        u32 t1v = pack2(pv[8*k+2], pv[8*k+3]);
        u32 t2v = pack2(pv[8*k+4], pv[8*k+5]);
        u32 t3v = pack2(pv[8*k+6], pv[8*k+7]);
        t2q[k] = make_uint4(t0v, t1v, t2v, t3v);
        u32 q0 = pack2((pv[8*k+0]-mean)*rstd*g2[c+0]+b2[c+0],
                       (pv[8*k+1]-mean)*rstd*g2[c+1]+b2[c+1]);
        u32 q1 = pack2((pv[8*k+2]-mean)*rstd*g2[c+2]+b2[c+2],
                       (pv[8*k+3]-mean)*rstd*g2[c+3]+b2[c+3]);
        u32 q2 = pack2((pv[8*k+4]-mean)*rstd*g2[c+4]+b2[c+4],
                       (pv[8*k+5]-mean)*rstd*g2[c+5]+b2[c+5]);
        u32 q3 = pack2((pv[8*k+6]-mean)*rstd*g2[c+6]+b2[c+6],
                       (pv[8*k+7]-mean)*rstd*g2[c+7]+b2[c+7]);
        hq[k] = make_uint4(q0, q1, q2, q3);
    }
}

// ---------------- K5: fc1 + exact GELU, LDS-free [v11] ----------------
__global__ __launch_bounds__(256) void k_fc1_m(const __hip_bfloat16* __restrict__ h2,
                                               const __hip_bfloat16* __restrict__ wb,
                                               const float* __restrict__ fb,
                                               __hip_bfloat16* __restrict__ m1, int t0)
{
    int tid = threadIdx.x;
    int wave = tid >> 6, lane = tid & 63;
    int quad = lane >> 4, l16 = lane & 15;
    int mbaseL = blockIdx.x * 64 + wave * 16;

    const __hip_bfloat16* ap = h2 + (long)(t0 + mbaseL + l16) * 96 + quad * 8;
    bf16x8 A0 = *(const bf16x8*)(ap);
    bf16x8 A1 = *(const bf16x8*)(ap + 32);
    bf16x8 A2 = *(const bf16x8*)(ap + 64);

    int tokL0 = mbaseL + quad * 4;
    const float is2 = 0.70710678118654752440f;

    for (int nt = 0; nt < 24; ++nt) {
        int r = nt * 16 + l16;
        const __hip_bfloat16* bp = wb + (long)r * 96 + quad * 8;
        bf16x8 B0 = *(const bf16x8*)(bp);
        bf16x8 B1 = *(const bf16x8*)(bp + 32);
        bf16x8 B2 = *(const bf16x8*)(bp + 64);
        float bias = fb[r];
        f32x4 acc = {0.f, 0.f, 0.f, 0.f};
        acc = MFMA(A0, B0, acc);
        acc = MFMA(A1, B1, acc);
        acc = MFMA(A2, B2, acc);
        #pragma unroll
        for (int rg = 0; rg < 4; ++rg) {
            float v = acc[rg] + bias;
            v = 0.5f * v * (1.f + erff(v * is2));
            m1[(long)(tokL0 + rg) * 384 + r] = __float2bfloat16(v);
        }
    }
}

// ---------------- K6: fc2 + residual(t2 bf16) -> out via MFMA [v11] ----------------
__global__ __launch_bounds__(256) void k_fc2_m(const __hip_bfloat16* __restrict__ m1,
                                               const float* __restrict__ fw,
                                               const float* __restrict__ fb,
                                               const __hip_bfloat16* __restrict__ t2,
                                               float* __restrict__ out, int t0)
{
    __shared__ short wsm[48 * 392];
    int tid = threadIdx.x;
    int wave = tid >> 6, lane = tid & 63;
    int quad = lane >> 4, l16 = lane & 15;
    int mbaseL = blockIdx.x * 128 + wave * 32;

    bf16x8 A[2][12];
    #pragma unroll
    for (int mm = 0; mm < 2; ++mm) {
        const __hip_bfloat16* ap = m1 + (long)(mbaseL + mm * 16 + l16) * 384 + quad * 8;
        #pragma unroll
        for (int kc = 0; kc < 12; ++kc)
            A[mm][kc] = *(const bf16x8*)(ap + kc * 32);
    }

    for (int ph = 0; ph < 2; ++ph) {
        if (ph) __syncthreads();
        for (int idx = tid; idx < 48 * 96; idx += 256) {
            int rr = idx / 96, cc = idx - rr * 96;
            float4 wv = ((const float4*)(fw + (long)(ph * 48 + rr) * 384))[cc];
            *(u64*)&wsm[rr * 392 + cc * 4] = pack4(wv.x, wv.y, wv.z, wv.w);
        }
        __syncthreads();
        for (int nt = 0; nt < 3; ++nt) {
            int n0 = nt * 16;
            const short* bp = &wsm[(n0 + l16) * 392 + quad * 8];
            bf16x8 B[12];
            #pragma unroll
            for (int kc = 0; kc < 12; ++kc)
                B[kc] = *(const bf16x8*)(bp + kc * 32);
            int c = ph * 48 + n0 + l16;
            float bias = fb[c];
            #pragma unroll
            for (int mm = 0; mm < 2; ++mm) {
                f32x4 acc = {0.f, 0.f, 0.f, 0.f};
                #pragma unroll
                for (int kc = 0; kc < 12; ++kc)
                    acc = MFMA(A[mm][kc], B[kc], acc);
                int tok0 = t0 + mbaseL + mm * 16 + quad * 4;
                #pragma unroll
                for (int rg = 0; rg < 4; ++rg) {
                    long g = (long)(tok0 + rg) * 96 + c;
                    out[g] = __bfloat162float(t2[g]) + acc[rg] + bias;
                }
            }
        }
    }
}

extern "C" void kernel_launch(void* const* d_in, const int* in_sizes, int n_in,
                              void* d_out, int out_size, void* d_ws, size_t ws_size,
                              hipStream_t stream)
{
    const float* x     = (const float*)d_in[0];
    const float* qkvw  = (const float*)d_in[1];
    const float* qkvb  = (const float*)d_in[2];
    const float* projw = (const float*)d_in[3];
    const float* projb = (const float*)d_in[4];
    const float* btab  = (const float*)d_in[5];
    const float* ln1g  = (const float*)d_in[6];
    const float* ln1b  = (const float*)d_in[7];
    const float* ln2g  = (const float*)d_in[8];
    const float* ln2b  = (const float*)d_in[9];
    const float* fc1w  = (const float*)d_in[10];
    const float* fc1b  = (const float*)d_in[11];
    const float* fc2w  = (const float*)d_in[12];
    const float* fc2b  = (const float*)d_in[13];
    float* out = (float*)d_out;

    if (ws_size < WS_NEED) {
        k_fill<<<49152, 256, 0, stream>>>(out, out_size);
        return;
    }

    // ws lifetimes (96 MiB, zero slack):
    //  [0,72)  : qkv(bf16) -> { pbuf bf16 [0,24) -> m1 chunk bf16 [0,48) ; t2 bf16 [48,72) }
    //  [72,96) : h(bf16) -> o(bf16) -> h2(bf16)
    // d_out tail (last 144KB): bf16 weights until fc2-ch1 overwrites (last dispatch).
    char* ws = (char*)d_ws;
    __hip_bfloat16* qkvB  = (__hip_bfloat16*)(ws);
    __hip_bfloat16* pbuf  = (__hip_bfloat16*)(ws);
    __hip_bfloat16* m1buf = (__hip_bfloat16*)(ws);
    __hip_bfloat16* t2buf = (__hip_bfloat16*)(ws + 50331648);
    __hip_bfloat16* hbuf  = (__hip_bfloat16*)(ws + 75497472);
    __hip_bfloat16* obuf  = hbuf;
    __hip_bfloat16* h2buf = hbuf;

    char* ob = (char*)d_out;
    __hip_bfloat16* wqb  = (__hip_bfloat16*)(ob + 50184192);  // 55296 B
    __hip_bfloat16* wpb  = (__hip_bfloat16*)(ob + 50239488);  // 18432 B
    __hip_bfloat16* wf1b = (__hip_bfloat16*)(ob + 50257920);  // 73728 B (ends 50331648)

    k_wcvt  <<<72,   256, 0, stream>>>(qkvw, projw, fc1w, (u64*)wqb, (u64*)wpb, (u64*)wf1b);
    k_ln1_c <<<2048, 256, 0, stream>>>(x, ln1g, ln1b, (u32*)hbuf);
    k_qkv_m <<<2048, 256, 0, stream>>>(hbuf, wqb, qkvb, qkvB);
    k_attn_m<<<1536, 256, 0, stream>>>(qkvB, btab, obuf);
    k_proj_nr<<<2048, 256, 0, stream>>>(obuf, wpb, projb, pbuf);
    k_addln2<<<2048, 256, 0, stream>>>(x, pbuf, ln2g, ln2b, (u32*)t2buf, (u32*)h2buf);
    for (int ch = 0; ch < 2; ++ch) {
        int t0 = ch * 65536;
        k_fc1_m<<<1024, 256, 0, stream>>>(h2buf, wf1b, fc1b, m1buf, t0);
        k_fc2_m<<<512,  256, 0, stream>>>(m1buf, fc2w, fc2b, t2buf, out, t0);
    }
}

// Round 16
// 368.534 us; speedup vs baseline: 1.0277x; 1.0162x over previous
//
#include <hip/hip_runtime.h>
#include <hip/hip_bf16.h>

typedef unsigned int u32;
typedef unsigned long long u64;
using bf16x8 = __attribute__((ext_vector_type(8))) short;
using f32x4  = __attribute__((ext_vector_type(4))) float;

#define QKV_STRIDE 12582912u   // elements per q/k/v tensor (512*3*256*32)
#define WS_NEED    100663296ull

__device__ __forceinline__ float bl(u32 u) { return __uint_as_float(u << 16); }
__device__ __forceinline__ float bh(u32 u) { return __uint_as_float(u & 0xffff0000u); }
__device__ __forceinline__ unsigned short bfbits(float f) {
    __hip_bfloat16 b = __float2bfloat16(f);
    return *(unsigned short*)&b;
}
__device__ __forceinline__ u32 pack2(float f0, float f1) {
    return ((u32)bfbits(f1) << 16) | (u32)bfbits(f0);
}
__device__ __forceinline__ u64 pack4(float f0, float f1, float f2, float f3) {
    return ((u64)pack2(f2, f3) << 32) | (u64)pack2(f0, f1);
}

#define MFMA(a, b, c) __builtin_amdgcn_mfma_f32_16x16x32_bf16(a, b, c, 0, 0, 0)

// ---------------- guard: ws too small -> sentinel 1000 ----------------
__global__ __launch_bounds__(256) void k_fill(float* __restrict__ out, int n)
{
    int i = blockIdx.x * 256 + threadIdx.x;
    if (i < n) out[i] = 1000.0f;
}

// ---------------- K0: f32->bf16 qkv/proj/fc1 weights into d_out tail ----------------
__global__ __launch_bounds__(256) void k_wcvt(const float* __restrict__ qkvw,
                                              const float* __restrict__ pw,
                                              const float* __restrict__ f1w,
                                              u64* __restrict__ wq,
                                              u64* __restrict__ wp,
                                              u64* __restrict__ wf1)
{
    int i = blockIdx.x * 256 + threadIdx.x;   // 18432 float4 total
    if (i < 6912) {
        float4 v = ((const float4*)qkvw)[i];
        wq[i] = pack4(v.x, v.y, v.z, v.w);
    } else if (i < 9216) {
        int j = i - 6912;
        float4 v = ((const float4*)pw)[j];
        wp[j] = pack4(v.x, v.y, v.z, v.w);
    } else if (i < 18432) {
        int j = i - 9216;
        float4 v = ((const float4*)f1w)[j];
        wf1[j] = pack4(v.x, v.y, v.z, v.w);
    }
}

// ---------------- K1: coalesced gather + LayerNorm1 -> h (bf16) [v11 form] ----------------
__global__ __launch_bounds__(256) void k_ln1_c(const float* __restrict__ x,
                                               const float* __restrict__ g1,
                                               const float* __restrict__ b1,
                                               u32* __restrict__ h)
{
    __shared__ float xs[96 * 128];
    __shared__ float ps[256], pss[256], mr[128], rs[128];
    int blk = blockIdx.x;
    int hh = blk & 127, d = (blk >> 7) & 3, bb = blk >> 9;
    long base = (long)bb * 6291456 + (long)d * 16384 + hh * 128;
    for (int i = threadIdx.x; i < 3072; i += 256) {
        int c = i >> 5, w4 = i & 31;
        ((float4*)xs)[i] = *(const float4*)(x + base + (long)c * 65536 + w4 * 4);
    }
    __syncthreads();

    int tid = threadIdx.x, half = tid >> 7, ww = tid & 127;
    int c0 = half * 48;
    float s = 0.f, ssq = 0.f;
    #pragma unroll 8
    for (int c = c0; c < c0 + 48; ++c) {
        float v = xs[c * 128 + ww];
        s += v; ssq += v * v;
    }
    ps[tid] = s; pss[tid] = ssq;
    __syncthreads();
    if (half == 0) {
        float st = ps[ww] + ps[128 + ww], sst = pss[ww] + pss[128 + ww];
        float mean = st * (1.f / 96.f);
        float var  = sst * (1.f / 96.f) - mean * mean;
        mr[ww] = mean; rs[ww] = rsqrtf(var + 1e-5f);
    }
    __syncthreads();
    float mean = mr[ww], rstd = rs[ww];

    int w = (bb << 8) + (hh >> 3) * 16 + (ww >> 3);
    int t = (w << 8) + d * 64 + (hh & 7) * 8 + (ww & 7);
    uint4* hq = (uint4*)(h + (long)t * 48 + half * 24);
    #pragma unroll
    for (int k = 0; k < 6; ++k) {
        int c = c0 + 8 * k;
        u32 q0 = pack2((xs[(c+0)*128+ww]-mean)*rstd*g1[c+0]+b1[c+0],
                       (xs[(c+1)*128+ww]-mean)*rstd*g1[c+1]+b1[c+1]);
        u32 q1 = pack2((xs[(c+2)*128+ww]-mean)*rstd*g1[c+2]+b1[c+2],
                       (xs[(c+3)*128+ww]-mean)*rstd*g1[c+3]+b1[c+3]);
        u32 q2 = pack2((xs[(c+4)*128+ww]-mean)*rstd*g1[c+4]+b1[c+4],
                       (xs[(c+5)*128+ww]-mean)*rstd*g1[c+5]+b1[c+5]);
        u32 q3 = pack2((xs[(c+6)*128+ww]-mean)*rstd*g1[c+6]+b1[c+6],
                       (xs[(c+7)*128+ww]-mean)*rstd*g1[c+7]+b1[c+7]);
        hq[k] = make_uint4(q0, q1, q2, q3);
    }
}

// ---------------- K2: QKV GEMM, LDS-free (bf16 weights from d_out tail) [v11] ----------------
__global__ __launch_bounds__(256) void k_qkv_m(const __hip_bfloat16* __restrict__ h,
                                               const __hip_bfloat16* __restrict__ wb,
                                               const float* __restrict__ qkvb,
                                               __hip_bfloat16* __restrict__ qkv)
{
    int tid = threadIdx.x;
    int wave = tid >> 6, lane = tid & 63;
    int quad = lane >> 4, l16 = lane & 15;
    int mbase = blockIdx.x * 64 + wave * 16;

    const __hip_bfloat16* ap = h + (long)(mbase + l16) * 96 + quad * 8;
    bf16x8 A0 = *(const bf16x8*)(ap);
    bf16x8 A1 = *(const bf16x8*)(ap + 32);
    bf16x8 A2 = *(const bf16x8*)(ap + 64);

    int tok0 = mbase + quad * 4;
    int w = tok0 >> 8, nn = tok0 & 255;

    for (int nt = 0; nt < 18; ++nt) {
        int n0 = nt * 16;
        const __hip_bfloat16* bp = wb + (n0 + l16) * 96 + quad * 8;
        bf16x8 B0 = *(const bf16x8*)(bp);
        bf16x8 B1 = *(const bf16x8*)(bp + 32);
        bf16x8 B2 = *(const bf16x8*)(bp + 64);
        int r    = n0 + l16;
        int type = n0 / 96;
        int head = (n0 % 96) / 32;
        int dd   = r & 31;
        float bias = qkvb[r];
        float scl  = (type == 0) ? 0.17677669529663687f : 1.0f;
        long tbase = (long)type * QKV_STRIDE;
        f32x4 acc = {0.f, 0.f, 0.f, 0.f};
        acc = MFMA(A0, B0, acc);
        acc = MFMA(A1, B1, acc);
        acc = MFMA(A2, B2, acc);
        long dst0 = tbase + (long)(w * 3 + head) * 8192 + nn * 32 + dd;
        #pragma unroll
        for (int rg = 0; rg < 4; ++rg)
            qkv[dst0 + (long)rg * 32] = __float2bfloat16((acc[rg] + bias) * scl);
    }
}

// ---------------- K3: window attention via MFMA [unchanged] ----------------
__global__ __launch_bounds__(256, 6) void k_attn_m(const __hip_bfloat16* __restrict__ qkv,
                                                   const float* __restrict__ btab,
                                                   __hip_bfloat16* __restrict__ o)
{
    __shared__ short vt[32 * 264];        // V^T [d][key], pitch 264 (16B-aligned)
    __shared__ float bsT[31 * 33];        // bias transposed: bsT[dx][dy], odd pitch
    int wh = blockIdx.x, head = wh % 3, w = wh / 3;
    int tid = threadIdx.x;

    const u32* vg = (const u32*)(qkv + 2u * QKV_STRIDE + (long)wh * 8192);
    for (int idx = tid; idx < 4096; idx += 256) {
        u32 pv = vg[idx];
        int kr = idx >> 4, d0 = (idx & 15) * 2;
        vt[d0 * 264 + kr]       = (short)(pv & 0xffffu);
        vt[(d0 + 1) * 264 + kr] = (short)(pv >> 16);
    }
    for (int idx = tid; idx < 961; idx += 256) {
        int c2 = idx / 31, r2 = idx - c2 * 31;
        bsT[c2 * 33 + r2] = btab[(r2 * 31 + c2) * 3 + head];
    }
    __syncthreads();

    int wave = tid >> 6, lane = tid & 63, quad = lane >> 4, l16 = lane & 15;
    const __hip_bfloat16* qb = qkv + (long)wh * 8192;
    const __hip_bfloat16* kb = qkv + QKV_STRIDE + (long)wh * 8192;

    int addrA = ((((lane >> 4) & 1) << 5) + l16) << 2;   // src lane (quad&1)*32 + l16
    int addrB = addrA + 64;                              // +16 lanes
    int addrI = (quad * 20) << 2;                        // lane 20*quad (+4*rg): inv for query quad*4+rg
    bool hiq  = (quad >= 2);

    #pragma unroll 1
    for (int g = 0; g < 4; ++g) {
        int qg = wave * 4 + g;
        bf16x8 qf = *(const bf16x8*)(qb + (qg * 16 + l16) * 32 + quad * 8);
        f32x4 a0 = {0.f, 0.f, 0.f, 0.f}, a1 = {0.f, 0.f, 0.f, 0.f};
        float lsum = 0.f;

        #pragma unroll 1
        for (int qt = 0; qt < 4; ++qt) {       // quarters of 64 keys, SEQUENTIAL
            f32x4 s[4];
            #pragma unroll
            for (int k4 = 0; k4 < 4; ++k4) {
                int kt = qt * 4 + k4;
                bf16x8 kkv = *(const bf16x8*)(kb + (kt * 16 + l16) * 32 + quad * 8);
                f32x4 z = {0.f, 0.f, 0.f, 0.f};
                s[k4] = MFMA(kkv, qf, z);
            }
            #pragma unroll
            for (int rg = 0; rg < 4; ++rg) {
                const float* bb = &bsT[(l16 - quad * 4 + 15 - rg) * 33 + qg];
                #pragma unroll
                for (int k4 = 0; k4 < 4; ++k4)
                    s[k4][rg] += bb[15 - qt * 4 - k4];
            }
            f32x4 vs = {0.f, 0.f, 0.f, 0.f};
            #pragma unroll
            for (int k4 = 0; k4 < 4; ++k4) {
                f32x4 e;
                #pragma unroll
                for (int rg = 0; rg < 4; ++rg) e[rg] = __expf(s[k4][rg]);
                s[k4] = e;
                vs += e;
            }
            lsum += vs[0] + vs[1] + vs[2] + vs[3];

            #pragma unroll
            for (int k2l = 0; k2l < 2; ++k2l) {
                int k2 = qt * 2 + k2l;
                u32 pe0 = pack2(s[2 * k2l][0],     s[2 * k2l][1]);
                u32 pe1 = pack2(s[2 * k2l][2],     s[2 * k2l][3]);
                u32 po0 = pack2(s[2 * k2l + 1][0], s[2 * k2l + 1][1]);
                u32 po1 = pack2(s[2 * k2l + 1][2], s[2 * k2l + 1][3]);
                u32 e0 = (u32)__builtin_amdgcn_ds_bpermute(addrA, (int)pe0);
                u32 o0 = (u32)__builtin_amdgcn_ds_bpermute(addrA, (int)po0);
                u32 e1 = (u32)__builtin_amdgcn_ds_bpermute(addrA, (int)pe1);
                u32 o1 = (u32)__builtin_amdgcn_ds_bpermute(addrA, (int)po1);
                u32 e2 = (u32)__builtin_amdgcn_ds_bpermute(addrB, (int)pe0);
                u32 o2 = (u32)__builtin_amdgcn_ds_bpermute(addrB, (int)po0);
                u32 e3 = (u32)__builtin_amdgcn_ds_bpermute(addrB, (int)pe1);
                u32 o3 = (u32)__builtin_amdgcn_ds_bpermute(addrB, (int)po1);
                union { u32 u[4]; bf16x8 v; } pu;
                pu.u[0] = hiq ? o0 : e0;
                pu.u[1] = hiq ? o1 : e1;
                pu.u[2] = hiq ? o2 : e2;
                pu.u[3] = hiq ? o3 : e3;
                bf16x8 v0 = *(const bf16x8*)&vt[l16 * 264 + k2 * 32 + quad * 8];
                bf16x8 v1 = *(const bf16x8*)&vt[(16 + l16) * 264 + k2 * 32 + quad * 8];
                a0 = MFMA(pu.v, v0, a0);
                a1 = MFMA(pu.v, v1, a1);
            }
        }

        lsum += __shfl_xor(lsum, 16);
        lsum += __shfl_xor(lsum, 32);
        float inv = 1.f / lsum;          // valid for query qg*16 + l16

        #pragma unroll
        for (int rg = 0; rg < 4; ++rg) {
            float irg = __uint_as_float(
                (u32)__builtin_amdgcn_ds_bpermute(addrI + (rg << 2), (int)__float_as_uint(inv)));
            int qrow = qg * 16 + quad * 4 + rg;
            __hip_bfloat16* op = o + (long)(w * 256 + qrow) * 96 + head * 32;
            op[l16]      = __float2bfloat16(a0[rg] * irg);
            op[16 + l16] = __float2bfloat16(a1[rg] * irg);
        }
    }
}

// ---------------- K4: FUSED proj + residual + LN2 -> t2 (bf16), h2 (bf16) ----------------
// v16: pbuf (25MB write + 25MB read) eliminated. Standard proj MFMA layout
// (lane(quad,l16) holds C[token=quad*4+rg][col=nt*16+l16]); per-token LN =
// sum_nt (in-register) + shfl_xor(1,2,4,8) over l16 (stays within quad group).
// Residual x gathered once into 96x68-pitch LDS tile (26.1KB -> 6 blocks/CU;
// pitch 68: stride-68 token-column reads = 2-way bank (free), f4 offsets 16B-aligned).
// Block = 64 consecutive tokens = one (w,d) 8x8 spatial patch of x (mapping
// inverse-checked against addln2's forward map).
__global__ __launch_bounds__(256) void k_projln(const __hip_bfloat16* __restrict__ o,
                                                const __hip_bfloat16* __restrict__ wb,
                                                const float* __restrict__ pb,
                                                const float* __restrict__ x,
                                                const float* __restrict__ g2,
                                                const float* __restrict__ b2,
                                                __hip_bfloat16* __restrict__ t2,
                                                __hip_bfloat16* __restrict__ h2)
{
    __shared__ float xs2[96 * 68];        // [channel][token-in-block], pitch 68
    int tid = threadIdx.x;
    int wave = tid >> 6, lane = tid & 63;
    int quad = lane >> 4, l16 = lane & 15;
    int mbase = blockIdx.x * 64;

    // x patch for tokens [mbase, mbase+64): w = mbase>>8, n0 = mbase&255, d = n0>>6
    int wfull = mbase >> 8, n0 = mbase & 255, d = n0 >> 6;
    int bb = wfull >> 8, wIdx = wfull & 255;
    long base = (long)bb * 6291456 + (long)d * 16384
              + (long)(wIdx >> 4) * 8 * 128 + (wIdx & 15) * 8;
    for (int i = tid; i < 1536; i += 256) {       // 96 ch x 8 rows x 2 float4
        int c = i >> 4, rem = i & 15, r8 = rem >> 1, f4 = rem & 1;
        float4 v = *(const float4*)(x + base + (long)c * 65536 + r8 * 128 + f4 * 4);
        *(float4*)&xs2[c * 68 + r8 * 8 + f4 * 4] = v;
    }

    int mtok = mbase + wave * 16;
    const __hip_bfloat16* ap = o + (long)(mtok + l16) * 96 + quad * 8;
    bf16x8 A0 = *(const bf16x8*)(ap);
    bf16x8 A1 = *(const bf16x8*)(ap + 32);
    bf16x8 A2 = *(const bf16x8*)(ap + 64);
    __syncthreads();

    int tl0 = wave * 16 + quad * 4;               // token-in-block base for this lane
    float v[6][4];
    float sum[4] = {0.f, 0.f, 0.f, 0.f}, ssq[4] = {0.f, 0.f, 0.f, 0.f};

    #pragma unroll
    for (int nt = 0; nt < 6; ++nt) {
        int n0c = nt * 16;
        const __hip_bfloat16* bp = wb + (n0c + l16) * 96 + quad * 8;
        bf16x8 B0 = *(const bf16x8*)(bp);
        bf16x8 B1 = *(const bf16x8*)(bp + 32);
        bf16x8 B2 = *(const bf16x8*)(bp + 64);
        int c = n0c + l16;
        float bias = pb[c];
        f32x4 acc = {0.f, 0.f, 0.f, 0.f};
        acc = MFMA(A0, B0, acc);
        acc = MFMA(A1, B1, acc);
        acc = MFMA(A2, B2, acc);
        #pragma unroll
        for (int rg = 0; rg < 4; ++rg) {
            float vv = acc[rg] + bias + xs2[c * 68 + tl0 + rg];
            v[nt][rg] = vv;
            sum[rg] += vv; ssq[rg] += vv * vv;
        }
    }
    // reduce across the 16 cols held by lanes of the same quad group
    #pragma unroll
    for (int m = 1; m < 16; m <<= 1) {
        #pragma unroll
        for (int rg = 0; rg < 4; ++rg) {
            sum[rg] += __shfl_xor(sum[rg], m);
            ssq[rg] += __shfl_xor(ssq[rg], m);
        }
    }
    float mean[4], rstd[4];
    #pragma unroll
    for (int rg = 0; rg < 4; ++rg) {
        mean[rg] = sum[rg] * (1.f / 96.f);
        float var = ssq[rg] * (1.f / 96.f) - mean[rg] * mean[rg];
        rstd[rg] = rsqrtf(var + 1e-5f);
    }

    int tok0 = mbase + tl0;
    #pragma unroll
    for (int nt = 0; nt < 6; ++nt) {
        int c = nt * 16 + l16;
        float gc = g2[c], bc = b2[c];
        #pragma unroll
        for (int rg = 0; rg < 4; ++rg) {
            long gidx = (long)(tok0 + rg) * 96 + c;
            float vv = v[nt][rg];
            t2[gidx] = __float2bfloat16(vv);
            h2[gidx] = __float2bfloat16((vv - mean[rg]) * rstd[rg] * gc + bc);
        }
    }
}

// ---------------- K5: fc1 + exact GELU, LDS-free [v11] ----------------
__global__ __launch_bounds__(256) void k_fc1_m(const __hip_bfloat16* __restrict__ h2,
                                               const __hip_bfloat16* __restrict__ wb,
                                               const float* __restrict__ fb,
                                               __hip_bfloat16* __restrict__ m1, int t0)
{
    int tid = threadIdx.x;
    int wave = tid >> 6, lane = tid & 63;
    int quad = lane >> 4, l16 = lane & 15;
    int mbaseL = blockIdx.x * 64 + wave * 16;

    const __hip_bfloat16* ap = h2 + (long)(t0 + mbaseL + l16) * 96 + quad * 8;
    bf16x8 A0 = *(const bf16x8*)(ap);
    bf16x8 A1 = *(const bf16x8*)(ap + 32);
    bf16x8 A2 = *(const bf16x8*)(ap + 64);

    int tokL0 = mbaseL + quad * 4;
    const float is2 = 0.70710678118654752440f;

    for (int nt = 0; nt < 24; ++nt) {
        int r = nt * 16 + l16;
        const __hip_bfloat16* bp = wb + (long)r * 96 + quad * 8;
        bf16x8 B0 = *(const bf16x8*)(bp);
        bf16x8 B1 = *(const bf16x8*)(bp + 32);
        bf16x8 B2 = *(const bf16x8*)(bp + 64);
        float bias = fb[r];
        f32x4 acc = {0.f, 0.f, 0.f, 0.f};
        acc = MFMA(A0, B0, acc);
        acc = MFMA(A1, B1, acc);
        acc = MFMA(A2, B2, acc);
        #pragma unroll
        for (int rg = 0; rg < 4; ++rg) {
            float v = acc[rg] + bias;
            v = 0.5f * v * (1.f + erff(v * is2));
            m1[(long)(tokL0 + rg) * 384 + r] = __float2bfloat16(v);
        }
    }
}

// ---------------- K6: fc2 + residual(t2 bf16) -> out via MFMA [v11] ----------------
__global__ __launch_bounds__(256) void k_fc2_m(const __hip_bfloat16* __restrict__ m1,
                                               const float* __restrict__ fw,
                                               const float* __restrict__ fb,
                                               const __hip_bfloat16* __restrict__ t2,
                                               float* __restrict__ out, int t0)
{
    __shared__ short wsm[48 * 392];
    int tid = threadIdx.x;
    int wave = tid >> 6, lane = tid & 63;
    int quad = lane >> 4, l16 = lane & 15;
    int mbaseL = blockIdx.x * 128 + wave * 32;

    bf16x8 A[2][12];
    #pragma unroll
    for (int mm = 0; mm < 2; ++mm) {
        const __hip_bfloat16* ap = m1 + (long)(mbaseL + mm * 16 + l16) * 384 + quad * 8;
        #pragma unroll
        for (int kc = 0; kc < 12; ++kc)
            A[mm][kc] = *(const bf16x8*)(ap + kc * 32);
    }

    for (int ph = 0; ph < 2; ++ph) {
        if (ph) __syncthreads();
        for (int idx = tid; idx < 48 * 96; idx += 256) {
            int rr = idx / 96, cc = idx - rr * 96;
            float4 wv = ((const float4*)(fw + (long)(ph * 48 + rr) * 384))[cc];
            *(u64*)&wsm[rr * 392 + cc * 4] = pack4(wv.x, wv.y, wv.z, wv.w);
        }
        __syncthreads();
        for (int nt = 0; nt < 3; ++nt) {
            int n0 = nt * 16;
            const short* bp = &wsm[(n0 + l16) * 392 + quad * 8];
            bf16x8 B[12];
            #pragma unroll
            for (int kc = 0; kc < 12; ++kc)
                B[kc] = *(const bf16x8*)(bp + kc * 32);
            int c = ph * 48 + n0 + l16;
            float bias = fb[c];
            #pragma unroll
            for (int mm = 0; mm < 2; ++mm) {
                f32x4 acc = {0.f, 0.f, 0.f, 0.f};
                #pragma unroll
                for (int kc = 0; kc < 12; ++kc)
                    acc = MFMA(A[mm][kc], B[kc], acc);
                int tok0 = t0 + mbaseL + mm * 16 + quad * 4;
                #pragma unroll
                for (int rg = 0; rg < 4; ++rg) {
                    long g = (long)(tok0 + rg) * 96 + c;
                    out[g] = __bfloat162float(t2[g]) + acc[rg] + bias;
                }
            }
        }
    }
}

extern "C" void kernel_launch(void* const* d_in, const int* in_sizes, int n_in,
                              void* d_out, int out_size, void* d_ws, size_t ws_size,
                              hipStream_t stream)
{
    const float* x     = (const float*)d_in[0];
    const float* qkvw  = (const float*)d_in[1];
    const float* qkvb  = (const float*)d_in[2];
    const float* projw = (const float*)d_in[3];
    const float* projb = (const float*)d_in[4];
    const float* btab  = (const float*)d_in[5];
    const float* ln1g  = (const float*)d_in[6];
    const float* ln1b  = (const float*)d_in[7];
    const float* ln2g  = (const float*)d_in[8];
    const float* ln2b  = (const float*)d_in[9];
    const float* fc1w  = (const float*)d_in[10];
    const float* fc1b  = (const float*)d_in[11];
    const float* fc2w  = (const float*)d_in[12];
    const float* fc2b  = (const float*)d_in[13];
    float* out = (float*)d_out;

    if (ws_size < WS_NEED) {
        k_fill<<<49152, 256, 0, stream>>>(out, out_size);
        return;
    }

    // ws lifetimes (96 MiB):
    //  [0,72)  : qkv(bf16) -> m1 chunk bf16 [0,48) ; t2 bf16 [48,72)
    //  [72,96) : h(bf16) -> o(bf16) -> h2(bf16)
    // d_out tail (last 144KB): bf16 weights until fc2-ch1 overwrites (last dispatch).
    char* ws = (char*)d_ws;
    __hip_bfloat16* qkvB  = (__hip_bfloat16*)(ws);
    __hip_bfloat16* m1buf = (__hip_bfloat16*)(ws);
    __hip_bfloat16* t2buf = (__hip_bfloat16*)(ws + 50331648);
    __hip_bfloat16* hbuf  = (__hip_bfloat16*)(ws + 75497472);
    __hip_bfloat16* obuf  = hbuf;
    __hip_bfloat16* h2buf = hbuf;

    char* ob = (char*)d_out;
    __hip_bfloat16* wqb  = (__hip_bfloat16*)(ob + 50184192);  // 55296 B
    __hip_bfloat16* wpb  = (__hip_bfloat16*)(ob + 50239488);  // 18432 B
    __hip_bfloat16* wf1b = (__hip_bfloat16*)(ob + 50257920);  // 73728 B (ends 50331648)

    k_wcvt  <<<72,   256, 0, stream>>>(qkvw, projw, fc1w, (u64*)wqb, (u64*)wpb, (u64*)wf1b);
    k_ln1_c <<<1024, 256, 0, stream>>>(x, ln1g, ln1b, (u32*)hbuf);
    k_qkv_m <<<2048, 256, 0, stream>>>(hbuf, wqb, qkvb, qkvB);
    k_attn_m<<<1536, 256, 0, stream>>>(qkvB, btab, obuf);
    k_projln<<<2048, 256, 0, stream>>>(obuf, wpb, projb, x, ln2g, ln2b, t2buf, h2buf);
    for (int ch = 0; ch < 2; ++ch) {
        int t0 = ch * 65536;
        k_fc1_m<<<1024, 256, 0, stream>>>(h2buf, wf1b, fc1b, m1buf, t0);
        k_fc2_m<<<512,  256, 0, stream>>>(m1buf, fc2w, fc2b, t2buf, out, t0);
    }
}